// Round 8
// baseline (532.451 us; speedup 1.0000x reference)
//
#include <hip/hip_runtime.h>
#include <hip/hip_fp16.h>
#include <math.h>

#define N_NODES 50000
#define N_EDGES 640000
#define NGRAPH  256
#define SCHUNK  1024
#define NCHUNK  49   // ceil(50000/1024)

typedef _Float16 half8_t __attribute__((ext_vector_type(8)));
typedef float floatx4 __attribute__((ext_vector_type(4)));

// ------------------------------------------------------------------
// Weight prep: convert all 7 [128,128] fp32 k-major weights into the
// fp16 transposed+swizzled layout the GEMM stages into LDS:
//   wt[m][n*128 + ((k>>3)^(n&15))*8 + (k&7)]
// ------------------------------------------------------------------
__global__ void k_wprep(const float* __restrict__ lin_w,
                        const float* __restrict__ conv_W,
                        _Float16* __restrict__ wt_g)
{
    int idx = blockIdx.x * 256 + threadIdx.x;
    if (idx >= 7 * 16384) return;
    int m = idx >> 14;
    int r = idx & 16383;
    int k = r >> 7;
    int n = r & 127;
    const float* W = (m == 0) ? lin_w : conv_W + (size_t)(m - 1) * 16384;
    float v = W[(size_t)k * 128 + n];
    int slot = (k >> 3) ^ (n & 15);
    wt_g[(size_t)m * 16384 + n * 128 + slot * 8 + (k & 7)] = (_Float16)v;
}

// ------------------------------------------------------------------
// MFMA GEMM: C16[M,128] = half(A16[M,128] @ W (+bias)).
// W pre-swizzled fp16; staging is a straight vector copy.
// Block 256 = 4 waves; wave computes 16 rows x 128 cols via 8 N-tiles.
// Optional fused attention projections a_s/a_d (fp32).
// ------------------------------------------------------------------
__global__ __launch_bounds__(256) void k_gemm16(
    const __half* __restrict__ A, const _Float16* __restrict__ wt,
    const float* __restrict__ bias, __half* __restrict__ C16, int M,
    const float* __restrict__ asrc, const float* __restrict__ adst,
    float* __restrict__ a_s, float* __restrict__ a_d)
{
    __shared__ _Float16 Wt[128 * 128];   // 32 KB
    int tid = threadIdx.x;
    {
        const float4* wsrc = (const float4*)wt;
        float4* wl = (float4*)Wt;
        #pragma unroll
        for (int r = 0; r < 8; ++r) wl[r * 256 + tid] = wsrc[r * 256 + tid];
    }
    __syncthreads();

    int lane = tid & 63;
    int wv = tid >> 6;
    int r0 = blockIdx.x * 64 + wv * 16;
    int cl = lane & 15;
    int ks = lane >> 4;             // k-chunk group 0..3

    int arow = r0 + cl; if (arow >= M) arow = M - 1;
    const _Float16* Arow = (const _Float16*)A + (size_t)arow * 128 + ks * 8;
    half8_t afrag[4];
    #pragma unroll
    for (int kk = 0; kk < 4; ++kk)
        afrag[kk] = *(const half8_t*)(Arow + kk * 32);

    floatx4 acc[8];
    #pragma unroll
    for (int nt = 0; nt < 8; ++nt) acc[nt] = (floatx4){0.f, 0.f, 0.f, 0.f};

    #pragma unroll
    for (int kk = 0; kk < 4; ++kk) {
        #pragma unroll
        for (int nt = 0; nt < 8; ++nt) {
            int n = nt * 16 + cl;
            int slot = (kk * 4 + ks) ^ cl;
            half8_t bfrag = *(const half8_t*)&Wt[n * 128 + slot * 8];
            acc[nt] = __builtin_amdgcn_mfma_f32_16x16x32_f16(afrag[kk], bfrag, acc[nt], 0, 0, 0);
        }
    }

    int rg = lane >> 4;   // row group for C/D
    #pragma unroll
    for (int nt = 0; nt < 8; ++nt) {
        float bv = bias ? bias[nt * 16 + cl] : 0.f;
        #pragma unroll
        for (int j = 0; j < 4; ++j) {
            int row = r0 + rg * 4 + j;
            if (row < M)
                C16[(size_t)row * 128 + nt * 16 + cl] = __float2half(acc[nt][j] + bv);
        }
    }

    if (a_s) {
        float s[4][4], d[4][4];
        #pragma unroll
        for (int h = 0; h < 4; ++h)
            #pragma unroll
            for (int j = 0; j < 4; ++j) { s[h][j] = 0.f; d[h][j] = 0.f; }
        #pragma unroll
        for (int nt = 0; nt < 8; ++nt) {
            int h = nt >> 1;
            float as = asrc[h * 32 + (nt & 1) * 16 + cl];
            float ad = adst[h * 32 + (nt & 1) * 16 + cl];
            #pragma unroll
            for (int j = 0; j < 4; ++j) {
                s[h][j] += acc[nt][j] * as;
                d[h][j] += acc[nt][j] * ad;
            }
        }
        #pragma unroll
        for (int h = 0; h < 4; ++h)
            #pragma unroll
            for (int j = 0; j < 4; ++j)
                #pragma unroll
                for (int k = 1; k < 16; k <<= 1) {
                    s[h][j] += __shfl_xor(s[h][j], k);
                    d[h][j] += __shfl_xor(d[h][j], k);
                }
        if (cl == 0) {
            #pragma unroll
            for (int j = 0; j < 4; ++j) {
                int row = r0 + rg * 4 + j;
                if (row < M) {
                    #pragma unroll
                    for (int h = 0; h < 4; ++h) {
                        a_s[row * 4 + h] = s[h][j];
                        a_d[row * 4 + h] = d[h][j];
                    }
                }
            }
        }
    }
}

// ------------------------------------------------------------------
__global__ void k_cast16(const float* __restrict__ in, __half* __restrict__ out, int n4) {
    int i = blockIdx.x * blockDim.x + threadIdx.x;
    if (i < n4) {
        float4 v = ((const float4*)in)[i];
        __half2 a = __floats2half2_rn(v.x, v.y);
        __half2 b = __floats2half2_rn(v.z, v.w);
        ((__half2*)out)[i * 2] = a;
        ((__half2*)out)[i * 2 + 1] = b;
    }
}

__global__ void k_zero_i(int* p, int n) {
    int i = blockIdx.x * blockDim.x + threadIdx.x;
    if (i < n) p[i] = 0;
}

__global__ void k_zero_f(float* p, int n) {
    int i = blockIdx.x * blockDim.x + threadIdx.x;
    if (i < n) p[i] = 0.f;
}

// ------------------------------------------------------------------
// CSR build; k_fill writes packed (src, ea) int2 directly in CSR order.
// ------------------------------------------------------------------
__global__ void k_deg(const int* __restrict__ dst, int* deg) {
    int e = blockIdx.x * blockDim.x + threadIdx.x;
    if (e < N_EDGES) atomicAdd(&deg[dst[e]], 1);
}

__global__ __launch_bounds__(256) void k_chunksum(const int* __restrict__ deg, int* cs) {
    __shared__ int r[256];
    int b = blockIdx.x;
    int acc = 0;
    for (int i = threadIdx.x; i < SCHUNK; i += 256) {
        int idx = b * SCHUNK + i;
        if (idx < N_NODES) acc += deg[idx];
    }
    r[threadIdx.x] = acc; __syncthreads();
    for (int s = 128; s > 0; s >>= 1) {
        if (threadIdx.x < s) r[threadIdx.x] += r[threadIdx.x + s];
        __syncthreads();
    }
    if (threadIdx.x == 0) cs[b] = r[0];
}

__global__ void k_scanbase(const int* cs, int* base, int* offs) {
    if (threadIdx.x == 0) {
        int run = 0;
        for (int b = 0; b < NCHUNK; ++b) { base[b] = run; run += cs[b]; }
        offs[N_NODES] = run;
    }
}

__global__ __launch_bounds__(1024) void k_scanlocal(
    const int* __restrict__ deg, const int* __restrict__ base,
    int* offs, int* cursor)
{
    __shared__ int s[1024];
    int b = blockIdx.x, t = threadIdx.x;
    int idx = b * SCHUNK + t;
    int d = (idx < N_NODES) ? deg[idx] : 0;
    s[t] = d; __syncthreads();
    for (int off = 1; off < 1024; off <<= 1) {
        int v = (t >= off) ? s[t - off] : 0;
        __syncthreads();
        s[t] += v; __syncthreads();
    }
    if (idx < N_NODES) {
        int ex = s[t] - d + base[b];
        offs[idx] = ex; cursor[idx] = ex;
    }
}

__global__ void k_fill(const int* __restrict__ src, const int* __restrict__ dst,
                       const float* __restrict__ ea, int* cursor,
                       int2* __restrict__ edata)
{
    int e = blockIdx.x * blockDim.x + threadIdx.x;
    if (e < N_EDGES) {
        int p = atomicAdd(&cursor[dst[e]], 1);
        edata[p] = make_int2(src[e], __float_as_int(ea[e]));
    }
}

// ------------------------------------------------------------------
// Single-pass fused attention aggregation (no max-subtraction:
// softmax is shift-invariant; logits are O(1), clamped at 80 for
// overflow insurance). One wave per node; lane = (slot q, col cl).
// Slot q handles edges q, q+4, ...; within a slot the 16 col-lanes
// share the edge's edata/a_s loads (same-address broadcast) and each
// computes its own head's logit + exp inline, then does the half8
// weighted gather. Zero cross-lane ops in the loop; den/acc reduced
// over slots via 2 static shfl_xor at the end.
// ------------------------------------------------------------------
__global__ __launch_bounds__(256) void k_attn3(
    const __half* __restrict__ wx16, const int2* __restrict__ edata,
    const float* __restrict__ a_s, const float* __restrict__ a_d,
    const int* __restrict__ offs, const __half* __restrict__ resid,
    __half* __restrict__ out)
{
    int lane = threadIdx.x & 63;
    int n = blockIdx.x * 4 + (threadIdx.x >> 6);
    int q = lane >> 4;        // edge slot 0..3
    int cl = lane & 15;       // col lane: 8 cols
    int c0 = cl * 8;
    int ht = cl >> 2;         // head of these 8 cols
    int off0 = offs[n], off1 = offs[n + 1];
    int cnt = off1 - off0;
    float adn = a_d[n * 4 + ht];
    const _Float16* wx = (const _Float16*)wx16;

    float den = 0.f;
    float acc[8];
    #pragma unroll
    for (int k = 0; k < 8; ++k) acc[k] = 0.f;

    #define STEP(jj) {                                                         \
        int2 ed = edata[off0 + (jj)];                                          \
        float t = a_s[ed.x * 4 + ht] + adn;                                    \
        t = (t > 0.f ? t : 0.2f * t) * __int_as_float(ed.y);                   \
        float w = __expf(fminf(t, 80.f));                                      \
        den += w;                                                              \
        half8_t g = *(const half8_t*)&wx[(size_t)ed.x * 128 + c0];             \
        acc[0] += w * (float)g[0]; acc[1] += w * (float)g[1];                  \
        acc[2] += w * (float)g[2]; acc[3] += w * (float)g[3];                  \
        acc[4] += w * (float)g[4]; acc[5] += w * (float)g[5];                  \
        acc[6] += w * (float)g[6]; acc[7] += w * (float)g[7]; }

    int j = q;
    for (; j + 4 < cnt; j += 8) { STEP(j); STEP(j + 4); }
    if (j < cnt) STEP(j);
    #undef STEP

    // reduce over the 4 slots (lane bits 4,5); cl (and thus ht) fixed
    den += __shfl_xor(den, 16);
    den += __shfl_xor(den, 32);
    #pragma unroll
    for (int k = 0; k < 8; ++k) {
        acc[k] += __shfl_xor(acc[k], 16);
        acc[k] += __shfl_xor(acc[k], 32);
    }

    if (q == 0) {
        float inv = 1.f / (den + 1e-16f);
        half8_t rv;
        if (resid) rv = *(const half8_t*)((const _Float16*)resid + (size_t)n * 128 + c0);
        half8_t o;
        #pragma unroll
        for (int k = 0; k < 8; ++k) {
            float r = acc[k] * inv;
            r = r > 0.f ? r : expm1f(r);
            if (resid) r += (float)rv[k];
            o[k] = (_Float16)r;
        }
        *(half8_t*)((_Float16*)out + (size_t)n * 128 + c0) = o;
    }
}

// ------------------------------------------------------------------
// Pool: chunked partial sums + atomic flush at segment boundaries.
// ------------------------------------------------------------------
__global__ __launch_bounds__(256) void k_pool2(
    const __half* __restrict__ h, const int* __restrict__ batch,
    float* __restrict__ pooled)
{
    int c = threadIdx.x & 127;
    int hf = threadIdx.x >> 7;
    int n0 = blockIdx.x * 64 + hf * 32;
    if (n0 >= N_NODES) return;
    int nend = n0 + 32; if (nend > N_NODES) nend = N_NODES;

    int g = batch[n0];
    float acc = 0.f;
    for (int n = n0; n < nend; ++n) {
        int bg = batch[n];
        if (bg != g) { atomicAdd(&pooled[g * 128 + c], acc); acc = 0.f; g = bg; }
        acc += __half2float(h[(size_t)n * 128 + c]);
    }
    atomicAdd(&pooled[g * 128 + c], acc);
}

// ------------------------------------------------------------------
// Linear + BatchNorm (+relu)
// ------------------------------------------------------------------
template <int K, int OC>
__global__ __launch_bounds__(256) void k_mlp(
    const float* __restrict__ in, const float* __restrict__ w,
    const float* __restrict__ b, const float* __restrict__ gam,
    const float* __restrict__ bet, float* __restrict__ out, int do_relu)
{
    __shared__ float2 red[256];
    int c = blockIdx.x, g = threadIdx.x;
    float val = b[c];
    #pragma unroll 8
    for (int k = 0; k < K; ++k) val += in[g * K + k] * w[k * OC + c];
    red[g] = make_float2(val, val * val);
    __syncthreads();
    for (int s = 128; s > 0; s >>= 1) {
        if (g < s) { red[g].x += red[g + s].x; red[g].y += red[g + s].y; }
        __syncthreads();
    }
    float mean = red[0].x * (1.f / 256.f);
    float var = red[0].y * (1.f / 256.f) - mean * mean;
    float y = (val - mean) * rsqrtf(var + 1e-5f) * gam[c] + bet[c];
    if (do_relu) y = fmaxf(y, 0.f);
    out[g * OC + c] = y;
}

// ------------------------------------------------------------------
extern "C" void kernel_launch(void* const* d_in, const int* in_sizes, int n_in,
                              void* d_out, int out_size, void* d_ws, size_t ws_size,
                              hipStream_t stream)
{
    const float* x         = (const float*)d_in[0];
    const float* edge_attr = (const float*)d_in[1];
    const float* lin_w     = (const float*)d_in[2];
    const float* lin_b     = (const float*)d_in[3];
    const float* conv_W    = (const float*)d_in[4];
    const float* conv_asrc = (const float*)d_in[5];
    const float* conv_adst = (const float*)d_in[6];
    const float* fc_w1 = (const float*)d_in[7];
    const float* fc_b1 = (const float*)d_in[8];
    const float* bn_g1 = (const float*)d_in[9];
    const float* bn_b1 = (const float*)d_in[10];
    const float* fc_w2 = (const float*)d_in[11];
    const float* fc_b2 = (const float*)d_in[12];
    const float* bn_g2 = (const float*)d_in[13];
    const float* bn_b2 = (const float*)d_in[14];
    const float* fc_w3 = (const float*)d_in[15];
    const float* fc_b3 = (const float*)d_in[16];
    const float* bn_g3 = (const float*)d_in[17];
    const float* bn_b3 = (const float*)d_in[18];
    const int* edge_index = (const int*)d_in[19];
    const int* batch      = (const int*)d_in[20];
    const int* srcp = edge_index;
    const int* dstp = edge_index + N_EDGES;
    float* out = (float*)d_out;

    char* ws = (char*)d_ws;
    __half* x16   = (__half*)ws; ws += (size_t)N_NODES * 128 * 2;
    __half* h_cur = (__half*)ws; ws += (size_t)N_NODES * 128 * 2;
    __half* h_tmp = (__half*)ws; ws += (size_t)N_NODES * 128 * 2;
    __half* wx16  = (__half*)ws; ws += (size_t)N_NODES * 128 * 2;
    float* a_s   = (float*)ws;  ws += (size_t)N_NODES * 4 * 4;
    float* a_d   = (float*)ws;  ws += (size_t)N_NODES * 4 * 4;
    float* pooled= (float*)ws;  ws += (size_t)NGRAPH * 128 * 4;
    float* z1    = (float*)ws;  ws += (size_t)NGRAPH * 64 * 4;
    float* z2    = (float*)ws;  ws += (size_t)NGRAPH * 32 * 4;
    int* deg     = (int*)ws;    ws += (size_t)N_NODES * 4;
    int* offs    = (int*)ws;    ws += (size_t)(N_NODES + 4) * 4;
    int* cursor  = (int*)ws;    ws += (size_t)N_NODES * 4;
    int2* edata  = (int2*)ws;   ws += (size_t)N_EDGES * 8;
    _Float16* wt_g = (_Float16*)ws; ws += (size_t)7 * 16384 * 2;
    int* cs      = (int*)ws;    ws += 64 * 4;
    int* cbase   = (int*)ws;    ws += 64 * 4;

    // --- CSR build + weight prep + casts ---
    k_zero_i<<<(N_NODES + 255) / 256, 256, 0, stream>>>(deg, N_NODES);
    k_deg<<<(N_EDGES + 255) / 256, 256, 0, stream>>>(dstp, deg);
    k_chunksum<<<NCHUNK, 256, 0, stream>>>(deg, cs);
    k_scanbase<<<1, 64, 0, stream>>>(cs, cbase, offs);
    k_scanlocal<<<NCHUNK, 1024, 0, stream>>>(deg, cbase, offs, cursor);
    k_fill<<<(N_EDGES + 255) / 256, 256, 0, stream>>>(srcp, dstp, edge_attr,
                                                      cursor, edata);
    k_wprep<<<(7 * 16384 + 255) / 256, 256, 0, stream>>>(lin_w, conv_W, wt_g);
    k_cast16<<<(N_NODES * 32 + 255) / 256, 256, 0, stream>>>(x, x16, N_NODES * 32);
    k_zero_f<<<(NGRAPH * 128 + 255) / 256, 256, 0, stream>>>(pooled, NGRAPH * 128);

    const int GGRID = (N_NODES + 63) / 64;

    // --- input linear ---
    k_gemm16<<<GGRID, 256, 0, stream>>>(x16, wt_g, lin_b, h_cur, N_NODES,
                                        nullptr, nullptr, nullptr, nullptr);

    // --- 3 residual scatter convs, 2 inner layers each ---
    for (int i = 0; i < 3; ++i) {
        const _Float16* W0 = wt_g + (size_t)(1 + i * 2 + 0) * 16384;
        const _Float16* W1 = wt_g + (size_t)(1 + i * 2 + 1) * 16384;
        const float* as0 = conv_asrc + (size_t)(i * 2 + 0) * 128;
        const float* as1 = conv_asrc + (size_t)(i * 2 + 1) * 128;
        const float* ad0 = conv_adst + (size_t)(i * 2 + 0) * 128;
        const float* ad1 = conv_adst + (size_t)(i * 2 + 1) * 128;

        k_gemm16<<<GGRID, 256, 0, stream>>>(h_cur, W0, nullptr, wx16, N_NODES,
                                            as0, ad0, a_s, a_d);
        k_attn3<<<N_NODES / 4, 256, 0, stream>>>(wx16, edata, a_s, a_d,
                                                 offs, nullptr, h_tmp);

        k_gemm16<<<GGRID, 256, 0, stream>>>(h_tmp, W1, nullptr, wx16, N_NODES,
                                            as1, ad1, a_s, a_d);
        k_attn3<<<N_NODES / 4, 256, 0, stream>>>(wx16, edata, a_s, a_d,
                                                 offs, h_cur, h_cur);
    }

    // --- pool + MLP head ---
    k_pool2<<<GGRID, 256, 0, stream>>>(h_cur, batch, pooled);
    k_mlp<128, 64><<<64, 256, 0, stream>>>(pooled, fc_w1, fc_b1, bn_g1, bn_b1, z1, 1);
    k_mlp<64, 32><<<32, 256, 0, stream>>>(z1, fc_w2, fc_b2, bn_g2, bn_b2, z2, 1);
    k_mlp<32, 10><<<10, 256, 0, stream>>>(z2, fc_w3, fc_b3, bn_g3, bn_b3, out, 0);
}

// Round 10
// 457.614 us; speedup vs baseline: 1.1635x; 1.1635x over previous
//
#include <hip/hip_runtime.h>
#include <hip/hip_fp16.h>
#include <math.h>

#define N_NODES 50000
#define N_EDGES 640000
#define NGRAPH  256
#define SCHUNK  1024
#define NCHUNK  49   // ceil(50000/1024)

typedef _Float16 half8_t __attribute__((ext_vector_type(8)));
typedef float floatx4 __attribute__((ext_vector_type(4)));

// ------------------------------------------------------------------
// Weight prep: convert all 7 [128,128] fp32 k-major weights into the
// fp16 transposed+swizzled layout the GEMM stages into LDS:
//   wt[m][n*128 + ((k>>3)^(n&15))*8 + (k&7)]
// ------------------------------------------------------------------
__global__ void k_wprep(const float* __restrict__ lin_w,
                        const float* __restrict__ conv_W,
                        _Float16* __restrict__ wt_g)
{
    int idx = blockIdx.x * 256 + threadIdx.x;
    if (idx >= 7 * 16384) return;
    int m = idx >> 14;
    int r = idx & 16383;
    int k = r >> 7;
    int n = r & 127;
    const float* W = (m == 0) ? lin_w : conv_W + (size_t)(m - 1) * 16384;
    float v = W[(size_t)k * 128 + n];
    int slot = (k >> 3) ^ (n & 15);
    wt_g[(size_t)m * 16384 + n * 128 + slot * 8 + (k & 7)] = (_Float16)v;
}

// ------------------------------------------------------------------
// Aux-tile prep with PROJECTION FOLDED THROUGH W (associativity:
// (A@W)@E == A@(W@E)). Caux[k][n] = sum_d W[k][h*32+d] * asrc[h][d]
// for n=h in 0..3, adst for n-4=h in 4..7, zero cols 8..15.
// Stored fp16, same swizzle as W. One MFMA tile then yields a_s/a_d
// directly from the GEMM's A-fragments.
// ------------------------------------------------------------------
__global__ void k_aprep(const float* __restrict__ conv_W,
                        const float* __restrict__ conv_asrc,
                        const float* __restrict__ conv_adst,
                        _Float16* __restrict__ aux_g)
{
    int idx = blockIdx.x * 256 + threadIdx.x;
    if (idx >= 6 * 2048) return;
    int li = idx >> 11;
    int r = idx & 2047;
    int k = r >> 4;       // 0..127 (input dim)
    int n = r & 15;       // 0..15 (aux col)
    float v = 0.f;
    if (n < 8) {
        int h = n & 3;
        const float* a = (n < 4) ? conv_asrc : conv_adst;
        const float* Wrow = conv_W + (size_t)li * 16384 + (size_t)k * 128 + h * 32;
        const float* av = a + (size_t)li * 128 + h * 32;
        #pragma unroll 8
        for (int d = 0; d < 32; ++d) v += Wrow[d] * av[d];
    }
    int slot = (k >> 3) ^ n;
    aux_g[(size_t)li * 2048 + n * 128 + slot * 8 + (k & 7)] = (_Float16)v;
}

// ------------------------------------------------------------------
// MFMA GEMM: C16[M,128] = half(A16[M,128] @ W (+bias)).
// W pre-swizzled fp16; staging is a straight vector copy.
// Block 256 = 4 waves; wave computes 16 rows x 128 cols via 8 N-tiles.
// a_s/a_d = A @ Caux (projection pre-folded through W) via 1 aux tile.
// ------------------------------------------------------------------
__global__ __launch_bounds__(256) void k_gemm16(
    const __half* __restrict__ A, const _Float16* __restrict__ wt,
    const _Float16* __restrict__ aux, const float* __restrict__ bias,
    __half* __restrict__ C16, int M,
    float* __restrict__ a_s, float* __restrict__ a_d)
{
    __shared__ _Float16 Wt[128 * 128];   // 32 KB
    __shared__ _Float16 Waux[16 * 128];  // 4 KB
    int tid = threadIdx.x;
    {
        const float4* wsrc = (const float4*)wt;
        float4* wl = (float4*)Wt;
        #pragma unroll
        for (int r = 0; r < 8; ++r) wl[r * 256 + tid] = wsrc[r * 256 + tid];
        if (aux) ((float4*)Waux)[tid] = ((const float4*)aux)[tid];
    }
    __syncthreads();

    int lane = tid & 63;
    int wv = tid >> 6;
    int r0 = blockIdx.x * 64 + wv * 16;
    int cl = lane & 15;
    int ks = lane >> 4;             // k-chunk group 0..3

    int arow = r0 + cl; if (arow >= M) arow = M - 1;
    const _Float16* Arow = (const _Float16*)A + (size_t)arow * 128 + ks * 8;
    half8_t afrag[4];
    #pragma unroll
    for (int kk = 0; kk < 4; ++kk)
        afrag[kk] = *(const half8_t*)(Arow + kk * 32);

    floatx4 acc[8];
    #pragma unroll
    for (int nt = 0; nt < 8; ++nt) acc[nt] = (floatx4){0.f, 0.f, 0.f, 0.f};

    #pragma unroll
    for (int kk = 0; kk < 4; ++kk) {
        #pragma unroll
        for (int nt = 0; nt < 8; ++nt) {
            int n = nt * 16 + cl;
            int slot = (kk * 4 + ks) ^ cl;
            half8_t bfrag = *(const half8_t*)&Wt[n * 128 + slot * 8];
            acc[nt] = __builtin_amdgcn_mfma_f32_16x16x32_f16(afrag[kk], bfrag, acc[nt], 0, 0, 0);
        }
    }

    int rg = lane >> 4;   // row group for C/D
    #pragma unroll
    for (int nt = 0; nt < 8; ++nt) {
        float bv = bias ? bias[nt * 16 + cl] : 0.f;
        #pragma unroll
        for (int j = 0; j < 4; ++j) {
            int row = r0 + rg * 4 + j;
            if (row < M)
                C16[(size_t)row * 128 + nt * 16 + cl] = __float2half(acc[nt][j] + bv);
        }
    }

    if (a_s) {
        floatx4 accP = (floatx4){0.f, 0.f, 0.f, 0.f};
        #pragma unroll
        for (int kk = 0; kk < 4; ++kk) {
            int slot = (kk * 4 + ks) ^ cl;
            half8_t bfrag = *(const half8_t*)&Waux[cl * 128 + slot * 8];
            accP = __builtin_amdgcn_mfma_f32_16x16x32_f16(afrag[kk], bfrag, accP, 0, 0, 0);
        }
        if (cl < 8) {
            float* dstp = (cl < 4) ? a_s : a_d;
            int h = cl & 3;
            #pragma unroll
            for (int j = 0; j < 4; ++j) {
                int row = r0 + rg * 4 + j;
                if (row < M) dstp[row * 4 + h] = accP[j];
            }
        }
    }
}

// ------------------------------------------------------------------
__global__ void k_cast16(const float* __restrict__ in, __half* __restrict__ out, int n4) {
    int i = blockIdx.x * blockDim.x + threadIdx.x;
    if (i < n4) {
        float4 v = ((const float4*)in)[i];
        __half2 a = __floats2half2_rn(v.x, v.y);
        __half2 b = __floats2half2_rn(v.z, v.w);
        ((__half2*)out)[i * 2] = a;
        ((__half2*)out)[i * 2 + 1] = b;
    }
}

__global__ void k_zero_i(int* p, int n) {
    int i = blockIdx.x * blockDim.x + threadIdx.x;
    if (i < n) p[i] = 0;
}

__global__ void k_zero_f(float* p, int n) {
    int i = blockIdx.x * blockDim.x + threadIdx.x;
    if (i < n) p[i] = 0.f;
}

// ------------------------------------------------------------------
// CSR build; k_fill writes packed (src, ea) int2 directly in CSR order.
// ------------------------------------------------------------------
__global__ void k_deg(const int* __restrict__ dst, int* deg) {
    int e = blockIdx.x * blockDim.x + threadIdx.x;
    if (e < N_EDGES) atomicAdd(&deg[dst[e]], 1);
}

__global__ __launch_bounds__(256) void k_chunksum(const int* __restrict__ deg, int* cs) {
    __shared__ int r[256];
    int b = blockIdx.x;
    int acc = 0;
    for (int i = threadIdx.x; i < SCHUNK; i += 256) {
        int idx = b * SCHUNK + i;
        if (idx < N_NODES) acc += deg[idx];
    }
    r[threadIdx.x] = acc; __syncthreads();
    for (int s = 128; s > 0; s >>= 1) {
        if (threadIdx.x < s) r[threadIdx.x] += r[threadIdx.x + s];
        __syncthreads();
    }
    if (threadIdx.x == 0) cs[b] = r[0];
}

__global__ void k_scanbase(const int* cs, int* base, int* offs) {
    if (threadIdx.x == 0) {
        int run = 0;
        for (int b = 0; b < NCHUNK; ++b) { base[b] = run; run += cs[b]; }
        offs[N_NODES] = run;
    }
}

__global__ __launch_bounds__(1024) void k_scanlocal(
    const int* __restrict__ deg, const int* __restrict__ base,
    int* offs, int* cursor)
{
    __shared__ int s[1024];
    int b = blockIdx.x, t = threadIdx.x;
    int idx = b * SCHUNK + t;
    int d = (idx < N_NODES) ? deg[idx] : 0;
    s[t] = d; __syncthreads();
    for (int off = 1; off < 1024; off <<= 1) {
        int v = (t >= off) ? s[t - off] : 0;
        __syncthreads();
        s[t] += v; __syncthreads();
    }
    if (idx < N_NODES) {
        int ex = s[t] - d + base[b];
        offs[idx] = ex; cursor[idx] = ex;
    }
}

__global__ void k_fill(const int* __restrict__ src, const int* __restrict__ dst,
                       const float* __restrict__ ea, int* cursor,
                       int2* __restrict__ edata)
{
    int e = blockIdx.x * blockDim.x + threadIdx.x;
    if (e < N_EDGES) {
        int p = atomicAdd(&cursor[dst[e]], 1);
        edata[p] = make_int2(src[e], __float_as_int(ea[e]));
    }
}

// ------------------------------------------------------------------
// Single-pass fused attention aggregation (softmax shift-invariance:
// no max pass; logits O(1), clamped at 80). One wave per node;
// lane = (slot q, col cl). ELU epilogue uses __expf(r)-1.
// ------------------------------------------------------------------
__global__ __launch_bounds__(256) void k_attn3(
    const __half* __restrict__ wx16, const int2* __restrict__ edata,
    const float* __restrict__ a_s, const float* __restrict__ a_d,
    const int* __restrict__ offs, const __half* __restrict__ resid,
    __half* __restrict__ out)
{
    int lane = threadIdx.x & 63;
    int n = blockIdx.x * 4 + (threadIdx.x >> 6);
    int q = lane >> 4;        // edge slot 0..3
    int cl = lane & 15;       // col lane: 8 cols
    int c0 = cl * 8;
    int ht = cl >> 2;         // head of these 8 cols
    int off0 = offs[n], off1 = offs[n + 1];
    int cnt = off1 - off0;
    float adn = a_d[n * 4 + ht];
    const _Float16* wx = (const _Float16*)wx16;

    float den = 0.f;
    float acc[8];
    #pragma unroll
    for (int k = 0; k < 8; ++k) acc[k] = 0.f;

    #define STEP(jj) {                                                         \
        int2 ed = edata[off0 + (jj)];                                          \
        float t = a_s[ed.x * 4 + ht] + adn;                                    \
        t = (t > 0.f ? t : 0.2f * t) * __int_as_float(ed.y);                   \
        float w = __expf(fminf(t, 80.f));                                      \
        den += w;                                                              \
        half8_t g = *(const half8_t*)&wx[(size_t)ed.x * 128 + c0];             \
        acc[0] += w * (float)g[0]; acc[1] += w * (float)g[1];                  \
        acc[2] += w * (float)g[2]; acc[3] += w * (float)g[3];                  \
        acc[4] += w * (float)g[4]; acc[5] += w * (float)g[5];                  \
        acc[6] += w * (float)g[6]; acc[7] += w * (float)g[7]; }

    int j = q;
    for (; j + 4 < cnt; j += 8) { STEP(j); STEP(j + 4); }
    if (j < cnt) STEP(j);
    #undef STEP

    // reduce over the 4 slots (lane bits 4,5); cl (and thus ht) fixed
    den += __shfl_xor(den, 16);
    den += __shfl_xor(den, 32);
    #pragma unroll
    for (int k = 0; k < 8; ++k) {
        acc[k] += __shfl_xor(acc[k], 16);
        acc[k] += __shfl_xor(acc[k], 32);
    }

    if (q == 0) {
        float inv = 1.f / (den + 1e-16f);
        half8_t rv;
        if (resid) rv = *(const half8_t*)((const _Float16*)resid + (size_t)n * 128 + c0);
        half8_t o;
        #pragma unroll
        for (int k = 0; k < 8; ++k) {
            float r = acc[k] * inv;
            r = r > 0.f ? r : (__expf(r) - 1.f);   // ELU, cheap form
            if (resid) r += (float)rv[k];
            o[k] = (_Float16)r;
        }
        *(half8_t*)((_Float16*)out + (size_t)n * 128 + c0) = o;
    }
}

// ------------------------------------------------------------------
// Pool: chunked partial sums + atomic flush at segment boundaries.
// ------------------------------------------------------------------
__global__ __launch_bounds__(256) void k_pool2(
    const __half* __restrict__ h, const int* __restrict__ batch,
    float* __restrict__ pooled)
{
    int c = threadIdx.x & 127;
    int hf = threadIdx.x >> 7;
    int n0 = blockIdx.x * 64 + hf * 32;
    if (n0 >= N_NODES) return;
    int nend = n0 + 32; if (nend > N_NODES) nend = N_NODES;

    int g = batch[n0];
    float acc = 0.f;
    for (int n = n0; n < nend; ++n) {
        int bg = batch[n];
        if (bg != g) { atomicAdd(&pooled[g * 128 + c], acc); acc = 0.f; g = bg; }
        acc += __half2float(h[(size_t)n * 128 + c]);
    }
    atomicAdd(&pooled[g * 128 + c], acc);
}

// ------------------------------------------------------------------
// Linear + BatchNorm (+relu)
// ------------------------------------------------------------------
template <int K, int OC>
__global__ __launch_bounds__(256) void k_mlp(
    const float* __restrict__ in, const float* __restrict__ w,
    const float* __restrict__ b, const float* __restrict__ gam,
    const float* __restrict__ bet, float* __restrict__ out, int do_relu)
{
    __shared__ float2 red[256];
    int c = blockIdx.x, g = threadIdx.x;
    float val = b[c];
    #pragma unroll 8
    for (int k = 0; k < K; ++k) val += in[g * K + k] * w[k * OC + c];
    red[g] = make_float2(val, val * val);
    __syncthreads();
    for (int s = 128; s > 0; s >>= 1) {
        if (g < s) { red[g].x += red[g + s].x; red[g].y += red[g + s].y; }
        __syncthreads();
    }
    float mean = red[0].x * (1.f / 256.f);
    float var = red[0].y * (1.f / 256.f) - mean * mean;
    float y = (val - mean) * rsqrtf(var + 1e-5f) * gam[c] + bet[c];
    if (do_relu) y = fmaxf(y, 0.f);
    out[g * OC + c] = y;
}

// ------------------------------------------------------------------
extern "C" void kernel_launch(void* const* d_in, const int* in_sizes, int n_in,
                              void* d_out, int out_size, void* d_ws, size_t ws_size,
                              hipStream_t stream)
{
    const float* x         = (const float*)d_in[0];
    const float* edge_attr = (const float*)d_in[1];
    const float* lin_w     = (const float*)d_in[2];
    const float* lin_b     = (const float*)d_in[3];
    const float* conv_W    = (const float*)d_in[4];
    const float* conv_asrc = (const float*)d_in[5];
    const float* conv_adst = (const float*)d_in[6];
    const float* fc_w1 = (const float*)d_in[7];
    const float* fc_b1 = (const float*)d_in[8];
    const float* bn_g1 = (const float*)d_in[9];
    const float* bn_b1 = (const float*)d_in[10];
    const float* fc_w2 = (const float*)d_in[11];
    const float* fc_b2 = (const float*)d_in[12];
    const float* bn_g2 = (const float*)d_in[13];
    const float* bn_b2 = (const float*)d_in[14];
    const float* fc_w3 = (const float*)d_in[15];
    const float* fc_b3 = (const float*)d_in[16];
    const float* bn_g3 = (const float*)d_in[17];
    const float* bn_b3 = (const float*)d_in[18];
    const int* edge_index = (const int*)d_in[19];
    const int* batch      = (const int*)d_in[20];
    const int* srcp = edge_index;
    const int* dstp = edge_index + N_EDGES;
    float* out = (float*)d_out;

    char* ws = (char*)d_ws;
    __half* x16   = (__half*)ws; ws += (size_t)N_NODES * 128 * 2;
    __half* h_cur = (__half*)ws; ws += (size_t)N_NODES * 128 * 2;
    __half* h_tmp = (__half*)ws; ws += (size_t)N_NODES * 128 * 2;
    __half* wx16  = (__half*)ws; ws += (size_t)N_NODES * 128 * 2;
    float* a_s   = (float*)ws;  ws += (size_t)N_NODES * 4 * 4;
    float* a_d   = (float*)ws;  ws += (size_t)N_NODES * 4 * 4;
    float* pooled= (float*)ws;  ws += (size_t)NGRAPH * 128 * 4;
    float* z1    = (float*)ws;  ws += (size_t)NGRAPH * 64 * 4;
    float* z2    = (float*)ws;  ws += (size_t)NGRAPH * 32 * 4;
    int* deg     = (int*)ws;    ws += (size_t)N_NODES * 4;
    int* offs    = (int*)ws;    ws += (size_t)(N_NODES + 4) * 4;
    int* cursor  = (int*)ws;    ws += (size_t)N_NODES * 4;
    int2* edata  = (int2*)ws;   ws += (size_t)N_EDGES * 8;
    _Float16* wt_g = (_Float16*)ws; ws += (size_t)7 * 16384 * 2;
    _Float16* wt_aux = (_Float16*)ws; ws += (size_t)6 * 2048 * 2;
    int* cs      = (int*)ws;    ws += 64 * 4;
    int* cbase   = (int*)ws;    ws += 64 * 4;

    // --- CSR build + weight prep + casts ---
    k_zero_i<<<(N_NODES + 255) / 256, 256, 0, stream>>>(deg, N_NODES);
    k_deg<<<(N_EDGES + 255) / 256, 256, 0, stream>>>(dstp, deg);
    k_chunksum<<<NCHUNK, 256, 0, stream>>>(deg, cs);
    k_scanbase<<<1, 64, 0, stream>>>(cs, cbase, offs);
    k_scanlocal<<<NCHUNK, 1024, 0, stream>>>(deg, cbase, offs, cursor);
    k_fill<<<(N_EDGES + 255) / 256, 256, 0, stream>>>(srcp, dstp, edge_attr,
                                                      cursor, edata);
    k_wprep<<<(7 * 16384 + 255) / 256, 256, 0, stream>>>(lin_w, conv_W, wt_g);
    k_aprep<<<(6 * 2048 + 255) / 256, 256, 0, stream>>>(conv_W, conv_asrc,
                                                        conv_adst, wt_aux);
    k_cast16<<<(N_NODES * 32 + 255) / 256, 256, 0, stream>>>(x, x16, N_NODES * 32);
    k_zero_f<<<(NGRAPH * 128 + 255) / 256, 256, 0, stream>>>(pooled, NGRAPH * 128);

    const int GGRID = (N_NODES + 63) / 64;

    // --- input linear ---
    k_gemm16<<<GGRID, 256, 0, stream>>>(x16, wt_g, nullptr, lin_b, h_cur, N_NODES,
                                        nullptr, nullptr);

    // --- 3 residual scatter convs, 2 inner layers each ---
    for (int i = 0; i < 3; ++i) {
        const _Float16* W0 = wt_g + (size_t)(1 + i * 2 + 0) * 16384;
        const _Float16* W1 = wt_g + (size_t)(1 + i * 2 + 1) * 16384;
        const _Float16* X0 = wt_aux + (size_t)(i * 2 + 0) * 2048;
        const _Float16* X1 = wt_aux + (size_t)(i * 2 + 1) * 2048;

        k_gemm16<<<GGRID, 256, 0, stream>>>(h_cur, W0, X0, nullptr, wx16, N_NODES,
                                            a_s, a_d);
        k_attn3<<<N_NODES / 4, 256, 0, stream>>>(wx16, edata, a_s, a_d,
                                                 offs, nullptr, h_tmp);

        k_gemm16<<<GGRID, 256, 0, stream>>>(h_tmp, W1, X1, nullptr, wx16, N_NODES,
                                            a_s, a_d);
        k_attn3<<<N_NODES / 4, 256, 0, stream>>>(wx16, edata, a_s, a_d,
                                                 offs, h_cur, h_cur);
    }

    // --- pool + MLP head ---
    k_pool2<<<GGRID, 256, 0, stream>>>(h_cur, batch, pooled);
    k_mlp<128, 64><<<64, 256, 0, stream>>>(pooled, fc_w1, fc_b1, bn_g1, bn_b1, z1, 1);
    k_mlp<64, 32><<<32, 256, 0, stream>>>(z1, fc_w2, fc_b2, bn_g2, bn_b2, z2, 1);
    k_mlp<32, 10><<<10, 256, 0, stream>>>(z2, fc_w3, fc_b3, bn_g3, bn_b3, out, 0);
}

// Round 11
// 419.400 us; speedup vs baseline: 1.2696x; 1.0911x over previous
//
#include <hip/hip_runtime.h>
#include <hip/hip_fp16.h>
#include <math.h>

#define N_NODES 50000
#define N_EDGES 640000
#define NGRAPH  256
#define NBUCK   196    // ceil(50000/256)
#define EPB     8192   // edges per hist/bin block
#define NBLK    79     // ceil(640000/8192)
#define BCAP    6144   // max edges per bucket (dataset max ~3.5K)

typedef _Float16 half8_t __attribute__((ext_vector_type(8)));
typedef float floatx4 __attribute__((ext_vector_type(4)));

// ------------------------------------------------------------------
// Weight prep: 7 [128,128] fp32 k-major weights -> fp16 transposed
// swizzled layout: wt[m][n*128 + ((k>>3)^(n&15))*8 + (k&7)]
// ------------------------------------------------------------------
__global__ void k_wprep(const float* __restrict__ lin_w,
                        const float* __restrict__ conv_W,
                        _Float16* __restrict__ wt_g)
{
    int idx = blockIdx.x * 256 + threadIdx.x;
    if (idx >= 7 * 16384) return;
    int m = idx >> 14;
    int r = idx & 16383;
    int k = r >> 7;
    int n = r & 127;
    const float* W = (m == 0) ? lin_w : conv_W + (size_t)(m - 1) * 16384;
    float v = W[(size_t)k * 128 + n];
    int slot = (k >> 3) ^ (n & 15);
    wt_g[(size_t)m * 16384 + n * 128 + slot * 8 + (k & 7)] = (_Float16)v;
}

// ------------------------------------------------------------------
// Aux-tile prep, projection folded through W: (A@W)@E == A@(W@E).
// Caux[k][n] = sum_d W[k][h*32+d]*asrc[h][d] (n=h<4), adst (4<=n<8).
// ------------------------------------------------------------------
__global__ void k_aprep(const float* __restrict__ conv_W,
                        const float* __restrict__ conv_asrc,
                        const float* __restrict__ conv_adst,
                        _Float16* __restrict__ aux_g)
{
    int idx = blockIdx.x * 256 + threadIdx.x;
    if (idx >= 6 * 2048) return;
    int li = idx >> 11;
    int r = idx & 2047;
    int k = r >> 4;
    int n = r & 15;
    float v = 0.f;
    if (n < 8) {
        int h = n & 3;
        const float* a = (n < 4) ? conv_asrc : conv_adst;
        const float* Wrow = conv_W + (size_t)li * 16384 + (size_t)k * 128 + h * 32;
        const float* av = a + (size_t)li * 128 + h * 32;
        #pragma unroll 8
        for (int d = 0; d < 32; ++d) v += Wrow[d] * av[d];
    }
    int slot = (k >> 3) ^ n;
    aux_g[(size_t)li * 2048 + n * 128 + slot * 8 + (k & 7)] = (_Float16)v;
}

// ------------------------------------------------------------------
// MFMA GEMM + folded attention projections (1 aux MFMA tile).
// ------------------------------------------------------------------
__global__ __launch_bounds__(256) void k_gemm16(
    const __half* __restrict__ A, const _Float16* __restrict__ wt,
    const _Float16* __restrict__ aux, const float* __restrict__ bias,
    __half* __restrict__ C16, int M,
    float* __restrict__ a_s, float* __restrict__ a_d)
{
    __shared__ _Float16 Wt[128 * 128];
    __shared__ _Float16 Waux[16 * 128];
    int tid = threadIdx.x;
    {
        const float4* wsrc = (const float4*)wt;
        float4* wl = (float4*)Wt;
        #pragma unroll
        for (int r = 0; r < 8; ++r) wl[r * 256 + tid] = wsrc[r * 256 + tid];
        if (aux) ((float4*)Waux)[tid] = ((const float4*)aux)[tid];
    }
    __syncthreads();

    int lane = tid & 63;
    int wv = tid >> 6;
    int r0 = blockIdx.x * 64 + wv * 16;
    int cl = lane & 15;
    int ks = lane >> 4;

    int arow = r0 + cl; if (arow >= M) arow = M - 1;
    const _Float16* Arow = (const _Float16*)A + (size_t)arow * 128 + ks * 8;
    half8_t afrag[4];
    #pragma unroll
    for (int kk = 0; kk < 4; ++kk)
        afrag[kk] = *(const half8_t*)(Arow + kk * 32);

    floatx4 acc[8];
    #pragma unroll
    for (int nt = 0; nt < 8; ++nt) acc[nt] = (floatx4){0.f, 0.f, 0.f, 0.f};

    #pragma unroll
    for (int kk = 0; kk < 4; ++kk) {
        #pragma unroll
        for (int nt = 0; nt < 8; ++nt) {
            int n = nt * 16 + cl;
            int slot = (kk * 4 + ks) ^ cl;
            half8_t bfrag = *(const half8_t*)&Wt[n * 128 + slot * 8];
            acc[nt] = __builtin_amdgcn_mfma_f32_16x16x32_f16(afrag[kk], bfrag, acc[nt], 0, 0, 0);
        }
    }

    int rg = lane >> 4;
    #pragma unroll
    for (int nt = 0; nt < 8; ++nt) {
        float bv = bias ? bias[nt * 16 + cl] : 0.f;
        #pragma unroll
        for (int j = 0; j < 4; ++j) {
            int row = r0 + rg * 4 + j;
            if (row < M)
                C16[(size_t)row * 128 + nt * 16 + cl] = __float2half(acc[nt][j] + bv);
        }
    }

    if (a_s) {
        floatx4 accP = (floatx4){0.f, 0.f, 0.f, 0.f};
        #pragma unroll
        for (int kk = 0; kk < 4; ++kk) {
            int slot = (kk * 4 + ks) ^ cl;
            half8_t bfrag = *(const half8_t*)&Waux[cl * 128 + slot * 8];
            accP = __builtin_amdgcn_mfma_f32_16x16x32_f16(afrag[kk], bfrag, accP, 0, 0, 0);
        }
        if (cl < 8) {
            float* dstp = (cl < 4) ? a_s : a_d;
            int h = cl & 3;
            #pragma unroll
            for (int j = 0; j < 4; ++j) {
                int row = r0 + rg * 4 + j;
                if (row < M) dstp[row * 4 + h] = accP[j];
            }
        }
    }
}

// ------------------------------------------------------------------
__global__ void k_cast16(const float* __restrict__ in, __half* __restrict__ out, int n4) {
    int i = blockIdx.x * blockDim.x + threadIdx.x;
    if (i < n4) {
        float4 v = ((const float4*)in)[i];
        __half2 a = __floats2half2_rn(v.x, v.y);
        __half2 b = __floats2half2_rn(v.z, v.w);
        ((__half2*)out)[i * 2] = a;
        ((__half2*)out)[i * 2 + 1] = b;
    }
}

__global__ void k_zero_f(float* p, int n) {
    int i = blockIdx.x * blockDim.x + threadIdx.x;
    if (i < n) p[i] = 0.f;
}

// ------------------------------------------------------------------
// CSR build via 2-level binning sort (no cross-XCD line ping-pong):
//  k_hist: per-block LDS histogram over coarse buckets (dst>>8)
//  k_scan2: per-(block,bucket) bases + bucketBase (single block)
//  k_bin: scatter into per-(block,bucket) sequential runs
//  k_sortfill: per-bucket LDS counting sort by dst&255 -> edata + offs
// ------------------------------------------------------------------
__global__ __launch_bounds__(256) void k_hist(const int* __restrict__ dst,
                                              int* __restrict__ counts)
{
    __shared__ int h[256];
    h[threadIdx.x] = 0;
    __syncthreads();
    int e0 = blockIdx.x * EPB;
    int e1 = e0 + EPB; if (e1 > N_EDGES) e1 = N_EDGES;
    for (int e = e0 + threadIdx.x; e < e1; e += 256)
        atomicAdd(&h[dst[e] >> 8], 1);
    __syncthreads();
    counts[blockIdx.x * 256 + threadIdx.x] = h[threadIdx.x];
}

__global__ __launch_bounds__(256) void k_scan2(const int* __restrict__ counts,
                                               int* __restrict__ base,
                                               int* __restrict__ bucketBase)
{
    __shared__ int tot[256];
    __shared__ int pref[257];
    int b = threadIdx.x;
    int s = 0;
    for (int blk = 0; blk < NBLK; ++blk) s += counts[blk * 256 + b];
    tot[b] = s;
    __syncthreads();
    if (b == 0) {
        int run = 0;
        for (int i = 0; i < 256; ++i) { pref[i] = run; run += tot[i]; }
        pref[256] = run;
    }
    __syncthreads();
    if (b <= NBUCK) bucketBase[b] = pref[b];
    int run = pref[b];
    for (int blk = 0; blk < NBLK; ++blk) {
        base[blk * 256 + b] = run;
        run += counts[blk * 256 + b];
    }
}

__global__ __launch_bounds__(256) void k_bin(const int* __restrict__ src,
                                             const int* __restrict__ dst,
                                             const float* __restrict__ ea,
                                             const int* __restrict__ base,
                                             int2* __restrict__ binned)
{
    __shared__ int cur[256];
    cur[threadIdx.x] = base[blockIdx.x * 256 + threadIdx.x];
    __syncthreads();
    int e0 = blockIdx.x * EPB;
    int e1 = e0 + EPB; if (e1 > N_EDGES) e1 = N_EDGES;
    for (int e = e0 + threadIdx.x; e < e1; e += 256) {
        int d = dst[e];
        int p = atomicAdd(&cur[d >> 8], 1);
        binned[p] = make_int2(src[e] | ((d & 255) << 16), __float_as_int(ea[e]));
    }
}

__global__ __launch_bounds__(256) void k_sortfill(const int2* __restrict__ binned,
                                                  const int* __restrict__ bucketBase,
                                                  int2* __restrict__ edata,
                                                  int* __restrict__ offs)
{
    __shared__ int bx[BCAP];
    __shared__ int by[BCAP];
    __shared__ int cnt[256];
    __shared__ int nb[256];
    int b = blockIdx.x;
    int p0 = bucketBase[b], p1 = bucketBase[b + 1];
    int m = p1 - p0;
    if (m > BCAP) m = BCAP;   // safety clamp (never hit on this dataset)
    cnt[threadIdx.x] = 0;
    __syncthreads();
    for (int i = threadIdx.x; i < m; i += 256) {
        int2 v = binned[p0 + i];
        bx[i] = v.x; by[i] = v.y;
        atomicAdd(&cnt[(v.x >> 16) & 255], 1);
    }
    __syncthreads();
    if (threadIdx.x == 0) {
        int run = 0;
        for (int i = 0; i < 256; ++i) { nb[i] = run; run += cnt[i]; }
    }
    __syncthreads();
    int node = b * 256 + threadIdx.x;
    if (node < N_NODES) offs[node] = p0 + nb[threadIdx.x];
    if (b == NBUCK - 1 && threadIdx.x == 0) offs[N_NODES] = p1;
    __syncthreads();
    cnt[threadIdx.x] = nb[threadIdx.x];   // reuse as cursor
    __syncthreads();
    for (int i = threadIdx.x; i < m; i += 256) {
        int dl = (bx[i] >> 16) & 255;
        int pos = atomicAdd(&cnt[dl], 1);
        edata[p0 + pos] = make_int2(bx[i] & 0xFFFF, by[i]);
    }
}

// ------------------------------------------------------------------
// Single-pass fused attention aggregation (shift-invariant softmax,
// no max pass; logits O(1), clamped at 80). One wave per node.
// ------------------------------------------------------------------
__global__ __launch_bounds__(256) void k_attn3(
    const __half* __restrict__ wx16, const int2* __restrict__ edata,
    const float* __restrict__ a_s, const float* __restrict__ a_d,
    const int* __restrict__ offs, const __half* __restrict__ resid,
    __half* __restrict__ out)
{
    int lane = threadIdx.x & 63;
    int n = blockIdx.x * 4 + (threadIdx.x >> 6);
    int q = lane >> 4;
    int cl = lane & 15;
    int c0 = cl * 8;
    int ht = cl >> 2;
    int off0 = offs[n], off1 = offs[n + 1];
    int cnt = off1 - off0;
    float adn = a_d[n * 4 + ht];
    const _Float16* wx = (const _Float16*)wx16;

    float den = 0.f;
    float acc[8];
    #pragma unroll
    for (int k = 0; k < 8; ++k) acc[k] = 0.f;

    #define STEP(jj) {                                                         \
        int2 ed = edata[off0 + (jj)];                                          \
        float t = a_s[ed.x * 4 + ht] + adn;                                    \
        t = (t > 0.f ? t : 0.2f * t) * __int_as_float(ed.y);                   \
        float w = __expf(fminf(t, 80.f));                                      \
        den += w;                                                              \
        half8_t g = *(const half8_t*)&wx[(size_t)ed.x * 128 + c0];             \
        acc[0] += w * (float)g[0]; acc[1] += w * (float)g[1];                  \
        acc[2] += w * (float)g[2]; acc[3] += w * (float)g[3];                  \
        acc[4] += w * (float)g[4]; acc[5] += w * (float)g[5];                  \
        acc[6] += w * (float)g[6]; acc[7] += w * (float)g[7]; }

    int j = q;
    for (; j + 4 < cnt; j += 8) { STEP(j); STEP(j + 4); }
    if (j < cnt) STEP(j);
    #undef STEP

    den += __shfl_xor(den, 16);
    den += __shfl_xor(den, 32);
    #pragma unroll
    for (int k = 0; k < 8; ++k) {
        acc[k] += __shfl_xor(acc[k], 16);
        acc[k] += __shfl_xor(acc[k], 32);
    }

    if (q == 0) {
        float inv = 1.f / (den + 1e-16f);
        half8_t rv;
        if (resid) rv = *(const half8_t*)((const _Float16*)resid + (size_t)n * 128 + c0);
        half8_t o;
        #pragma unroll
        for (int k = 0; k < 8; ++k) {
            float r = acc[k] * inv;
            r = r > 0.f ? r : (__expf(r) - 1.f);   // ELU, cheap form
            if (resid) r += (float)rv[k];
            o[k] = (_Float16)r;
        }
        *(half8_t*)((_Float16*)out + (size_t)n * 128 + c0) = o;
    }
}

// ------------------------------------------------------------------
// Pool: chunked partial sums + atomic flush at segment boundaries.
// ------------------------------------------------------------------
__global__ __launch_bounds__(256) void k_pool2(
    const __half* __restrict__ h, const int* __restrict__ batch,
    float* __restrict__ pooled)
{
    int c = threadIdx.x & 127;
    int hf = threadIdx.x >> 7;
    int n0 = blockIdx.x * 64 + hf * 32;
    if (n0 >= N_NODES) return;
    int nend = n0 + 32; if (nend > N_NODES) nend = N_NODES;

    int g = batch[n0];
    float acc = 0.f;
    for (int n = n0; n < nend; ++n) {
        int bg = batch[n];
        if (bg != g) { atomicAdd(&pooled[g * 128 + c], acc); acc = 0.f; g = bg; }
        acc += __half2float(h[(size_t)n * 128 + c]);
    }
    atomicAdd(&pooled[g * 128 + c], acc);
}

// ------------------------------------------------------------------
// Linear + BatchNorm (+relu)
// ------------------------------------------------------------------
template <int K, int OC>
__global__ __launch_bounds__(256) void k_mlp(
    const float* __restrict__ in, const float* __restrict__ w,
    const float* __restrict__ b, const float* __restrict__ gam,
    const float* __restrict__ bet, float* __restrict__ out, int do_relu)
{
    __shared__ float2 red[256];
    int c = blockIdx.x, g = threadIdx.x;
    float val = b[c];
    #pragma unroll 8
    for (int k = 0; k < K; ++k) val += in[g * K + k] * w[k * OC + c];
    red[g] = make_float2(val, val * val);
    __syncthreads();
    for (int s = 128; s > 0; s >>= 1) {
        if (g < s) { red[g].x += red[g + s].x; red[g].y += red[g + s].y; }
        __syncthreads();
    }
    float mean = red[0].x * (1.f / 256.f);
    float var = red[0].y * (1.f / 256.f) - mean * mean;
    float y = (val - mean) * rsqrtf(var + 1e-5f) * gam[c] + bet[c];
    if (do_relu) y = fmaxf(y, 0.f);
    out[g * OC + c] = y;
}

// ------------------------------------------------------------------
extern "C" void kernel_launch(void* const* d_in, const int* in_sizes, int n_in,
                              void* d_out, int out_size, void* d_ws, size_t ws_size,
                              hipStream_t stream)
{
    const float* x         = (const float*)d_in[0];
    const float* edge_attr = (const float*)d_in[1];
    const float* lin_w     = (const float*)d_in[2];
    const float* lin_b     = (const float*)d_in[3];
    const float* conv_W    = (const float*)d_in[4];
    const float* conv_asrc = (const float*)d_in[5];
    const float* conv_adst = (const float*)d_in[6];
    const float* fc_w1 = (const float*)d_in[7];
    const float* fc_b1 = (const float*)d_in[8];
    const float* bn_g1 = (const float*)d_in[9];
    const float* bn_b1 = (const float*)d_in[10];
    const float* fc_w2 = (const float*)d_in[11];
    const float* fc_b2 = (const float*)d_in[12];
    const float* bn_g2 = (const float*)d_in[13];
    const float* bn_b2 = (const float*)d_in[14];
    const float* fc_w3 = (const float*)d_in[15];
    const float* fc_b3 = (const float*)d_in[16];
    const float* bn_g3 = (const float*)d_in[17];
    const float* bn_b3 = (const float*)d_in[18];
    const int* edge_index = (const int*)d_in[19];
    const int* batch      = (const int*)d_in[20];
    const int* srcp = edge_index;
    const int* dstp = edge_index + N_EDGES;
    float* out = (float*)d_out;

    char* ws = (char*)d_ws;
    __half* x16   = (__half*)ws; ws += (size_t)N_NODES * 128 * 2;
    __half* h_cur = (__half*)ws; ws += (size_t)N_NODES * 128 * 2;
    __half* h_tmp = (__half*)ws; ws += (size_t)N_NODES * 128 * 2;
    __half* wx16  = (__half*)ws; ws += (size_t)N_NODES * 128 * 2;
    float* a_s   = (float*)ws;  ws += (size_t)N_NODES * 4 * 4;
    float* a_d   = (float*)ws;  ws += (size_t)N_NODES * 4 * 4;
    float* pooled= (float*)ws;  ws += (size_t)NGRAPH * 128 * 4;
    float* z1    = (float*)ws;  ws += (size_t)NGRAPH * 64 * 4;
    float* z2    = (float*)ws;  ws += (size_t)NGRAPH * 32 * 4;
    int* offs    = (int*)ws;    ws += (size_t)(N_NODES + 4) * 4;
    int2* edata  = (int2*)ws;   ws += (size_t)N_EDGES * 8;
    int2* binned = (int2*)ws;   ws += (size_t)N_EDGES * 8;
    int* counts  = (int*)ws;    ws += (size_t)NBLK * 256 * 4;
    int* base    = (int*)ws;    ws += (size_t)NBLK * 256 * 4;
    int* bucketBase = (int*)ws; ws += 256 * 4;
    _Float16* wt_g = (_Float16*)ws; ws += (size_t)7 * 16384 * 2;
    _Float16* wt_aux = (_Float16*)ws; ws += (size_t)6 * 2048 * 2;

    // --- CSR build (binning sort) + weight prep + casts ---
    k_hist<<<NBLK, 256, 0, stream>>>(dstp, counts);
    k_scan2<<<1, 256, 0, stream>>>(counts, base, bucketBase);
    k_bin<<<NBLK, 256, 0, stream>>>(srcp, dstp, edge_attr, base, binned);
    k_sortfill<<<NBUCK, 256, 0, stream>>>(binned, bucketBase, edata, offs);
    k_wprep<<<(7 * 16384 + 255) / 256, 256, 0, stream>>>(lin_w, conv_W, wt_g);
    k_aprep<<<(6 * 2048 + 255) / 256, 256, 0, stream>>>(conv_W, conv_asrc,
                                                        conv_adst, wt_aux);
    k_cast16<<<(N_NODES * 32 + 255) / 256, 256, 0, stream>>>(x, x16, N_NODES * 32);
    k_zero_f<<<(NGRAPH * 128 + 255) / 256, 256, 0, stream>>>(pooled, NGRAPH * 128);

    const int GGRID = (N_NODES + 63) / 64;

    // --- input linear ---
    k_gemm16<<<GGRID, 256, 0, stream>>>(x16, wt_g, nullptr, lin_b, h_cur, N_NODES,
                                        nullptr, nullptr);

    // --- 3 residual scatter convs, 2 inner layers each ---
    for (int i = 0; i < 3; ++i) {
        const _Float16* W0 = wt_g + (size_t)(1 + i * 2 + 0) * 16384;
        const _Float16* W1 = wt_g + (size_t)(1 + i * 2 + 1) * 16384;
        const _Float16* X0 = wt_aux + (size_t)(i * 2 + 0) * 2048;
        const _Float16* X1 = wt_aux + (size_t)(i * 2 + 1) * 2048;

        k_gemm16<<<GGRID, 256, 0, stream>>>(h_cur, W0, X0, nullptr, wx16, N_NODES,
                                            a_s, a_d);
        k_attn3<<<N_NODES / 4, 256, 0, stream>>>(wx16, edata, a_s, a_d,
                                                 offs, nullptr, h_tmp);

        k_gemm16<<<GGRID, 256, 0, stream>>>(h_tmp, W1, X1, nullptr, wx16, N_NODES,
                                            a_s, a_d);
        k_attn3<<<N_NODES / 4, 256, 0, stream>>>(wx16, edata, a_s, a_d,
                                                 offs, h_cur, h_cur);
    }

    // --- pool + MLP head ---
    k_pool2<<<GGRID, 256, 0, stream>>>(h_cur, batch, pooled);
    k_mlp<128, 64><<<64, 256, 0, stream>>>(pooled, fc_w1, fc_b1, bn_g1, bn_b1, z1, 1);
    k_mlp<64, 32><<<32, 256, 0, stream>>>(z1, fc_w2, fc_b2, bn_g2, bn_b2, z2, 1);
    k_mlp<32, 10><<<10, 256, 0, stream>>>(z2, fc_w3, fc_b3, bn_g3, bn_b3, out, 0);
}

// Round 12
// 384.206 us; speedup vs baseline: 1.3858x; 1.0916x over previous
//
#include <hip/hip_runtime.h>
#include <hip/hip_fp16.h>
#include <math.h>

#define N_NODES 50000
#define N_EDGES 640000
#define NGRAPH  256
#define NBUCK   196    // ceil(50000/256)
#define EPB     8192   // edges per hist/bin block
#define NBLK    79     // ceil(640000/8192)
#define BCAP    6144   // max edges per bucket (dataset max ~3.5K)

typedef _Float16 half8_t __attribute__((ext_vector_type(8)));
typedef float floatx4 __attribute__((ext_vector_type(4)));

// ------------------------------------------------------------------
// Weight prep: 7 [128,128] fp32 k-major weights -> fp16 transposed
// swizzled layout: wt[m][n*128 + ((k>>3)^(n&15))*8 + (k&7)]
// ------------------------------------------------------------------
__global__ void k_wprep(const float* __restrict__ lin_w,
                        const float* __restrict__ conv_W,
                        _Float16* __restrict__ wt_g)
{
    int idx = blockIdx.x * 256 + threadIdx.x;
    if (idx >= 7 * 16384) return;
    int m = idx >> 14;
    int r = idx & 16383;
    int k = r >> 7;
    int n = r & 127;
    const float* W = (m == 0) ? lin_w : conv_W + (size_t)(m - 1) * 16384;
    float v = W[(size_t)k * 128 + n];
    int slot = (k >> 3) ^ (n & 15);
    wt_g[(size_t)m * 16384 + n * 128 + slot * 8 + (k & 7)] = (_Float16)v;
}

// ------------------------------------------------------------------
// Aux-tile prep, projection folded through W: (A@W)@E == A@(W@E).
// ------------------------------------------------------------------
__global__ void k_aprep(const float* __restrict__ conv_W,
                        const float* __restrict__ conv_asrc,
                        const float* __restrict__ conv_adst,
                        _Float16* __restrict__ aux_g)
{
    int idx = blockIdx.x * 256 + threadIdx.x;
    if (idx >= 6 * 2048) return;
    int li = idx >> 11;
    int r = idx & 2047;
    int k = r >> 4;
    int n = r & 15;
    float v = 0.f;
    if (n < 8) {
        int h = n & 3;
        const float* a = (n < 4) ? conv_asrc : conv_adst;
        const float* Wrow = conv_W + (size_t)li * 16384 + (size_t)k * 128 + h * 32;
        const float* av = a + (size_t)li * 128 + h * 32;
        #pragma unroll 8
        for (int d = 0; d < 32; ++d) v += Wrow[d] * av[d];
    }
    int slot = (k >> 3) ^ n;
    aux_g[(size_t)li * 2048 + n * 128 + slot * 8 + (k & 7)] = (_Float16)v;
}

// ------------------------------------------------------------------
// MFMA GEMM + folded attention projections (1 aux MFMA tile).
// ------------------------------------------------------------------
__global__ __launch_bounds__(256) void k_gemm16(
    const __half* __restrict__ A, const _Float16* __restrict__ wt,
    const _Float16* __restrict__ aux, const float* __restrict__ bias,
    __half* __restrict__ C16, int M,
    float* __restrict__ a_s, float* __restrict__ a_d)
{
    __shared__ _Float16 Wt[128 * 128];
    __shared__ _Float16 Waux[16 * 128];
    int tid = threadIdx.x;
    {
        const float4* wsrc = (const float4*)wt;
        float4* wl = (float4*)Wt;
        #pragma unroll
        for (int r = 0; r < 8; ++r) wl[r * 256 + tid] = wsrc[r * 256 + tid];
        if (aux) ((float4*)Waux)[tid] = ((const float4*)aux)[tid];
    }
    __syncthreads();

    int lane = tid & 63;
    int wv = tid >> 6;
    int r0 = blockIdx.x * 64 + wv * 16;
    int cl = lane & 15;
    int ks = lane >> 4;

    int arow = r0 + cl; if (arow >= M) arow = M - 1;
    const _Float16* Arow = (const _Float16*)A + (size_t)arow * 128 + ks * 8;
    half8_t afrag[4];
    #pragma unroll
    for (int kk = 0; kk < 4; ++kk)
        afrag[kk] = *(const half8_t*)(Arow + kk * 32);

    floatx4 acc[8];
    #pragma unroll
    for (int nt = 0; nt < 8; ++nt) acc[nt] = (floatx4){0.f, 0.f, 0.f, 0.f};

    #pragma unroll
    for (int kk = 0; kk < 4; ++kk) {
        #pragma unroll
        for (int nt = 0; nt < 8; ++nt) {
            int n = nt * 16 + cl;
            int slot = (kk * 4 + ks) ^ cl;
            half8_t bfrag = *(const half8_t*)&Wt[n * 128 + slot * 8];
            acc[nt] = __builtin_amdgcn_mfma_f32_16x16x32_f16(afrag[kk], bfrag, acc[nt], 0, 0, 0);
        }
    }

    int rg = lane >> 4;
    #pragma unroll
    for (int nt = 0; nt < 8; ++nt) {
        float bv = bias ? bias[nt * 16 + cl] : 0.f;
        #pragma unroll
        for (int j = 0; j < 4; ++j) {
            int row = r0 + rg * 4 + j;
            if (row < M)
                C16[(size_t)row * 128 + nt * 16 + cl] = __float2half(acc[nt][j] + bv);
        }
    }

    if (a_s) {
        floatx4 accP = (floatx4){0.f, 0.f, 0.f, 0.f};
        #pragma unroll
        for (int kk = 0; kk < 4; ++kk) {
            int slot = (kk * 4 + ks) ^ cl;
            half8_t bfrag = *(const half8_t*)&Waux[cl * 128 + slot * 8];
            accP = __builtin_amdgcn_mfma_f32_16x16x32_f16(afrag[kk], bfrag, accP, 0, 0, 0);
        }
        if (cl < 8) {
            float* dstp = (cl < 4) ? a_s : a_d;
            int h = cl & 3;
            #pragma unroll
            for (int j = 0; j < 4; ++j) {
                int row = r0 + rg * 4 + j;
                if (row < M) dstp[row * 4 + h] = accP[j];
            }
        }
    }
}

// ------------------------------------------------------------------
__global__ void k_cast16(const float* __restrict__ in, __half* __restrict__ out, int n4) {
    int i = blockIdx.x * blockDim.x + threadIdx.x;
    if (i < n4) {
        float4 v = ((const float4*)in)[i];
        __half2 a = __floats2half2_rn(v.x, v.y);
        __half2 b = __floats2half2_rn(v.z, v.w);
        ((__half2*)out)[i * 2] = a;
        ((__half2*)out)[i * 2 + 1] = b;
    }
}

__global__ void k_zero_f(float* p, int n) {
    int i = blockIdx.x * blockDim.x + threadIdx.x;
    if (i < n) p[i] = 0.f;
}

// ------------------------------------------------------------------
// CSR build via 2-level binning sort.
// ------------------------------------------------------------------
__global__ __launch_bounds__(256) void k_hist(const int* __restrict__ dst,
                                              int* __restrict__ counts)
{
    __shared__ int h[256];
    h[threadIdx.x] = 0;
    __syncthreads();
    int e0 = blockIdx.x * EPB;
    int e1 = e0 + EPB; if (e1 > N_EDGES) e1 = N_EDGES;
    for (int e = e0 + threadIdx.x; e < e1; e += 256)
        atomicAdd(&h[dst[e] >> 8], 1);
    __syncthreads();
    counts[blockIdx.x * 256 + threadIdx.x] = h[threadIdx.x];
}

__global__ __launch_bounds__(256) void k_scan2(const int* __restrict__ counts,
                                               int* __restrict__ base,
                                               int* __restrict__ bucketBase)
{
    __shared__ int tot[256];
    __shared__ int pref[257];
    int b = threadIdx.x;
    int s = 0;
    for (int blk = 0; blk < NBLK; ++blk) s += counts[blk * 256 + b];
    tot[b] = s;
    __syncthreads();
    if (b == 0) {
        int run = 0;
        for (int i = 0; i < 256; ++i) { pref[i] = run; run += tot[i]; }
        pref[256] = run;
    }
    __syncthreads();
    if (b <= NBUCK) bucketBase[b] = pref[b];
    int run = pref[b];
    for (int blk = 0; blk < NBLK; ++blk) {
        base[blk * 256 + b] = run;
        run += counts[blk * 256 + b];
    }
}

__global__ __launch_bounds__(256) void k_bin(const int* __restrict__ src,
                                             const int* __restrict__ dst,
                                             const float* __restrict__ ea,
                                             const int* __restrict__ base,
                                             int2* __restrict__ binned)
{
    __shared__ int cur[256];
    cur[threadIdx.x] = base[blockIdx.x * 256 + threadIdx.x];
    __syncthreads();
    int e0 = blockIdx.x * EPB;
    int e1 = e0 + EPB; if (e1 > N_EDGES) e1 = N_EDGES;
    for (int e = e0 + threadIdx.x; e < e1; e += 256) {
        int d = dst[e];
        int p = atomicAdd(&cur[d >> 8], 1);
        binned[p] = make_int2(src[e] | ((d & 255) << 16), __float_as_int(ea[e]));
    }
}

__global__ __launch_bounds__(256) void k_sortfill(const int2* __restrict__ binned,
                                                  const int* __restrict__ bucketBase,
                                                  int2* __restrict__ edata,
                                                  int* __restrict__ offs)
{
    __shared__ int bx[BCAP];
    __shared__ int by[BCAP];
    __shared__ int cnt[256];
    __shared__ int nb[256];
    int b = blockIdx.x;
    int p0 = bucketBase[b], p1 = bucketBase[b + 1];
    int m = p1 - p0;
    if (m > BCAP) m = BCAP;
    cnt[threadIdx.x] = 0;
    __syncthreads();
    for (int i = threadIdx.x; i < m; i += 256) {
        int2 v = binned[p0 + i];
        bx[i] = v.x; by[i] = v.y;
        atomicAdd(&cnt[(v.x >> 16) & 255], 1);
    }
    __syncthreads();
    if (threadIdx.x == 0) {
        int run = 0;
        for (int i = 0; i < 256; ++i) { nb[i] = run; run += cnt[i]; }
    }
    __syncthreads();
    int node = b * 256 + threadIdx.x;
    if (node < N_NODES) offs[node] = p0 + nb[threadIdx.x];
    if (b == NBUCK - 1 && threadIdx.x == 0) offs[N_NODES] = p1;
    __syncthreads();
    cnt[threadIdx.x] = nb[threadIdx.x];
    __syncthreads();
    for (int i = threadIdx.x; i < m; i += 256) {
        int dl = (bx[i] >> 16) & 255;
        int pos = atomicAdd(&cnt[dl], 1);
        edata[p0 + pos] = make_int2(bx[i] & 0xFFFF, by[i]);
    }
}

// ------------------------------------------------------------------
// Fused attention aggregation, 2 nodes per wave.
// lane = (node-half nh, slot q 0..3, col-lane cl 0..7 x 16 cols).
// Each STEP wave-inst covers 8 edges (2 nodes x 4 slots); each lane
// gathers 32B of the wx row. Per-lane loop with exec-masking handles
// degree mismatch between the paired nodes. Shift-invariant softmax
// (no max pass, clamp 80); cheap ELU.
// ------------------------------------------------------------------
__global__ __launch_bounds__(256) void k_attn4(
    const __half* __restrict__ wx16, const int2* __restrict__ edata,
    const float* __restrict__ a_s, const float* __restrict__ a_d,
    const int* __restrict__ offs, const __half* __restrict__ resid,
    __half* __restrict__ out)
{
    int lane = threadIdx.x & 63;
    int wid = threadIdx.x >> 6;
    int nh = lane >> 5;                 // node half
    int n = blockIdx.x * 8 + wid * 2 + nh;
    int q = (lane >> 3) & 3;            // edge slot 0..3
    int cl = lane & 7;                  // col lane: 16 cols
    int c0 = cl * 16;
    int ht = cl >> 1;                   // head of these cols
    int off0 = offs[n], off1 = offs[n + 1];
    int cnt = off1 - off0;
    float adn = a_d[n * 4 + ht];
    const _Float16* wx = (const _Float16*)wx16;

    float den = 0.f;
    float acc[16];
    #pragma unroll
    for (int k = 0; k < 16; ++k) acc[k] = 0.f;

    #define STEP(jj) {                                                         \
        int2 ed = edata[off0 + (jj)];                                          \
        float t = a_s[ed.x * 4 + ht] + adn;                                    \
        t = (t > 0.f ? t : 0.2f * t) * __int_as_float(ed.y);                   \
        float w = __expf(fminf(t, 80.f));                                      \
        den += w;                                                              \
        const _Float16* rp = &wx[(size_t)ed.x * 128 + c0];                     \
        half8_t g0 = *(const half8_t*)rp;                                      \
        half8_t g1 = *(const half8_t*)(rp + 8);                                \
        acc[0]  += w * (float)g0[0]; acc[1]  += w * (float)g0[1];              \
        acc[2]  += w * (float)g0[2]; acc[3]  += w * (float)g0[3];              \
        acc[4]  += w * (float)g0[4]; acc[5]  += w * (float)g0[5];              \
        acc[6]  += w * (float)g0[6]; acc[7]  += w * (float)g0[7];              \
        acc[8]  += w * (float)g1[0]; acc[9]  += w * (float)g1[1];              \
        acc[10] += w * (float)g1[2]; acc[11] += w * (float)g1[3];              \
        acc[12] += w * (float)g1[4]; acc[13] += w * (float)g1[5];              \
        acc[14] += w * (float)g1[6]; acc[15] += w * (float)g1[7]; }

    int j = q;
    for (; j + 4 < cnt; j += 8) { STEP(j); STEP(j + 4); }
    if (j < cnt) STEP(j);
    #undef STEP

    // reduce over slots (lane bits 3,4); node half (bit 5) untouched
    den += __shfl_xor(den, 8);
    den += __shfl_xor(den, 16);
    #pragma unroll
    for (int k = 0; k < 16; ++k) {
        acc[k] += __shfl_xor(acc[k], 8);
        acc[k] += __shfl_xor(acc[k], 16);
    }

    if (q == 0) {
        float inv = 1.f / (den + 1e-16f);
        const _Float16* rvp = resid ? (const _Float16*)resid + (size_t)n * 128 + c0 : nullptr;
        half8_t rv0, rv1;
        if (resid) { rv0 = *(const half8_t*)rvp; rv1 = *(const half8_t*)(rvp + 8); }
        half8_t o0, o1;
        #pragma unroll
        for (int k = 0; k < 8; ++k) {
            float r = acc[k] * inv;
            r = r > 0.f ? r : (__expf(r) - 1.f);
            if (resid) r += (float)rv0[k];
            o0[k] = (_Float16)r;
        }
        #pragma unroll
        for (int k = 0; k < 8; ++k) {
            float r = acc[8 + k] * inv;
            r = r > 0.f ? r : (__expf(r) - 1.f);
            if (resid) r += (float)rv1[k];
            o1[k] = (_Float16)r;
        }
        _Float16* op = (_Float16*)out + (size_t)n * 128 + c0;
        *(half8_t*)op = o0;
        *(half8_t*)(op + 8) = o1;
    }
}

// ------------------------------------------------------------------
// Pool: chunked partial sums + atomic flush at segment boundaries.
// ------------------------------------------------------------------
__global__ __launch_bounds__(256) void k_pool2(
    const __half* __restrict__ h, const int* __restrict__ batch,
    float* __restrict__ pooled)
{
    int c = threadIdx.x & 127;
    int hf = threadIdx.x >> 7;
    int n0 = blockIdx.x * 64 + hf * 32;
    if (n0 >= N_NODES) return;
    int nend = n0 + 32; if (nend > N_NODES) nend = N_NODES;

    int g = batch[n0];
    float acc = 0.f;
    for (int n = n0; n < nend; ++n) {
        int bg = batch[n];
        if (bg != g) { atomicAdd(&pooled[g * 128 + c], acc); acc = 0.f; g = bg; }
        acc += __half2float(h[(size_t)n * 128 + c]);
    }
    atomicAdd(&pooled[g * 128 + c], acc);
}

// ------------------------------------------------------------------
// Linear + BatchNorm (+relu)
// ------------------------------------------------------------------
template <int K, int OC>
__global__ __launch_bounds__(256) void k_mlp(
    const float* __restrict__ in, const float* __restrict__ w,
    const float* __restrict__ b, const float* __restrict__ gam,
    const float* __restrict__ bet, float* __restrict__ out, int do_relu)
{
    __shared__ float2 red[256];
    int c = blockIdx.x, g = threadIdx.x;
    float val = b[c];
    #pragma unroll 8
    for (int k = 0; k < K; ++k) val += in[g * K + k] * w[k * OC + c];
    red[g] = make_float2(val, val * val);
    __syncthreads();
    for (int s = 128; s > 0; s >>= 1) {
        if (g < s) { red[g].x += red[g + s].x; red[g].y += red[g + s].y; }
        __syncthreads();
    }
    float mean = red[0].x * (1.f / 256.f);
    float var = red[0].y * (1.f / 256.f) - mean * mean;
    float y = (val - mean) * rsqrtf(var + 1e-5f) * gam[c] + bet[c];
    if (do_relu) y = fmaxf(y, 0.f);
    out[g * OC + c] = y;
}

// ------------------------------------------------------------------
extern "C" void kernel_launch(void* const* d_in, const int* in_sizes, int n_in,
                              void* d_out, int out_size, void* d_ws, size_t ws_size,
                              hipStream_t stream)
{
    const float* x         = (const float*)d_in[0];
    const float* edge_attr = (const float*)d_in[1];
    const float* lin_w     = (const float*)d_in[2];
    const float* lin_b     = (const float*)d_in[3];
    const float* conv_W    = (const float*)d_in[4];
    const float* conv_asrc = (const float*)d_in[5];
    const float* conv_adst = (const float*)d_in[6];
    const float* fc_w1 = (const float*)d_in[7];
    const float* fc_b1 = (const float*)d_in[8];
    const float* bn_g1 = (const float*)d_in[9];
    const float* bn_b1 = (const float*)d_in[10];
    const float* fc_w2 = (const float*)d_in[11];
    const float* fc_b2 = (const float*)d_in[12];
    const float* bn_g2 = (const float*)d_in[13];
    const float* bn_b2 = (const float*)d_in[14];
    const float* fc_w3 = (const float*)d_in[15];
    const float* fc_b3 = (const float*)d_in[16];
    const float* bn_g3 = (const float*)d_in[17];
    const float* bn_b3 = (const float*)d_in[18];
    const int* edge_index = (const int*)d_in[19];
    const int* batch      = (const int*)d_in[20];
    const int* srcp = edge_index;
    const int* dstp = edge_index + N_EDGES;
    float* out = (float*)d_out;

    char* ws = (char*)d_ws;
    __half* x16   = (__half*)ws; ws += (size_t)N_NODES * 128 * 2;
    __half* h_cur = (__half*)ws; ws += (size_t)N_NODES * 128 * 2;
    __half* h_tmp = (__half*)ws; ws += (size_t)N_NODES * 128 * 2;
    __half* wx16  = (__half*)ws; ws += (size_t)N_NODES * 128 * 2;
    float* a_s   = (float*)ws;  ws += (size_t)N_NODES * 4 * 4;
    float* a_d   = (float*)ws;  ws += (size_t)N_NODES * 4 * 4;
    float* pooled= (float*)ws;  ws += (size_t)NGRAPH * 128 * 4;
    float* z1    = (float*)ws;  ws += (size_t)NGRAPH * 64 * 4;
    float* z2    = (float*)ws;  ws += (size_t)NGRAPH * 32 * 4;
    int* offs    = (int*)ws;    ws += (size_t)(N_NODES + 4) * 4;
    int2* edata  = (int2*)ws;   ws += (size_t)N_EDGES * 8;
    int2* binned = (int2*)ws;   ws += (size_t)N_EDGES * 8;
    int* counts  = (int*)ws;    ws += (size_t)NBLK * 256 * 4;
    int* base    = (int*)ws;    ws += (size_t)NBLK * 256 * 4;
    int* bucketBase = (int*)ws; ws += 256 * 4;
    _Float16* wt_g = (_Float16*)ws; ws += (size_t)7 * 16384 * 2;
    _Float16* wt_aux = (_Float16*)ws; ws += (size_t)6 * 2048 * 2;

    // --- CSR build (binning sort) + weight prep + casts ---
    k_hist<<<NBLK, 256, 0, stream>>>(dstp, counts);
    k_scan2<<<1, 256, 0, stream>>>(counts, base, bucketBase);
    k_bin<<<NBLK, 256, 0, stream>>>(srcp, dstp, edge_attr, base, binned);
    k_sortfill<<<NBUCK, 256, 0, stream>>>(binned, bucketBase, edata, offs);
    k_wprep<<<(7 * 16384 + 255) / 256, 256, 0, stream>>>(lin_w, conv_W, wt_g);
    k_aprep<<<(6 * 2048 + 255) / 256, 256, 0, stream>>>(conv_W, conv_asrc,
                                                        conv_adst, wt_aux);
    k_cast16<<<(N_NODES * 32 + 255) / 256, 256, 0, stream>>>(x, x16, N_NODES * 32);
    k_zero_f<<<(NGRAPH * 128 + 255) / 256, 256, 0, stream>>>(pooled, NGRAPH * 128);

    const int GGRID = (N_NODES + 63) / 64;
    const int AGRID = (N_NODES + 7) / 8;

    // --- input linear ---
    k_gemm16<<<GGRID, 256, 0, stream>>>(x16, wt_g, nullptr, lin_b, h_cur, N_NODES,
                                        nullptr, nullptr);

    // --- 3 residual scatter convs, 2 inner layers each ---
    for (int i = 0; i < 3; ++i) {
        const _Float16* W0 = wt_g + (size_t)(1 + i * 2 + 0) * 16384;
        const _Float16* W1 = wt_g + (size_t)(1 + i * 2 + 1) * 16384;
        const _Float16* X0 = wt_aux + (size_t)(i * 2 + 0) * 2048;
        const _Float16* X1 = wt_aux + (size_t)(i * 2 + 1) * 2048;

        k_gemm16<<<GGRID, 256, 0, stream>>>(h_cur, W0, X0, nullptr, wx16, N_NODES,
                                            a_s, a_d);
        k_attn4<<<AGRID, 256, 0, stream>>>(wx16, edata, a_s, a_d,
                                           offs, nullptr, h_tmp);

        k_gemm16<<<GGRID, 256, 0, stream>>>(h_tmp, W1, X1, nullptr, wx16, N_NODES,
                                            a_s, a_d);
        k_attn4<<<AGRID, 256, 0, stream>>>(wx16, edata, a_s, a_d,
                                           offs, h_cur, h_cur);
    }

    // --- pool + MLP head ---
    k_pool2<<<GGRID, 256, 0, stream>>>(h_cur, batch, pooled);
    k_mlp<128, 64><<<64, 256, 0, stream>>>(pooled, fc_w1, fc_b1, bn_g1, bn_b1, z1, 1);
    k_mlp<64, 32><<<32, 256, 0, stream>>>(z1, fc_w2, fc_b2, bn_g2, bn_b2, z2, 1);
    k_mlp<32, 10><<<10, 256, 0, stream>>>(z2, fc_w3, fc_b3, bn_g3, bn_b3, out, 0);
}

// Round 13
// 374.212 us; speedup vs baseline: 1.4229x; 1.0267x over previous
//
#include <hip/hip_runtime.h>
#include <hip/hip_fp16.h>
#include <math.h>

#define N_NODES 50000
#define N_EDGES 640000
#define NGRAPH  256
#define NBUCK   196    // ceil(50000/256)
#define EPB     8192   // edges per hist/bin block
#define NBLK    79     // ceil(640000/8192)
#define BCAP    6144   // max edges per bucket (dataset max ~3.5K)

// k_prep block-range partition
#define PB_HIST  NBLK            // 79
#define PB_WPREP 448             // 7*16384/256
#define PB_APREP 48              // 6*2048/256
#define PB_ZERO  128             // 256*128/256
#define PREP_GRID (PB_HIST + PB_WPREP + PB_APREP + PB_ZERO)

typedef _Float16 half8_t __attribute__((ext_vector_type(8)));
typedef float floatx4 __attribute__((ext_vector_type(4)));

// ------------------------------------------------------------------
// Fused prologue: [0,79) dst-histogram | [79,527) W->fp16 swizzle |
// [527,575) aux-tile (projection folded through W) | [575,703) zero pooled.
// ------------------------------------------------------------------
__global__ __launch_bounds__(256) void k_prep(
    const int* __restrict__ dst, int* __restrict__ counts,
    const float* __restrict__ lin_w, const float* __restrict__ conv_W,
    _Float16* __restrict__ wt_g,
    const float* __restrict__ conv_asrc, const float* __restrict__ conv_adst,
    _Float16* __restrict__ aux_g,
    float* __restrict__ pooled)
{
    __shared__ int h[256];
    int b = blockIdx.x;
    if (b < PB_HIST) {
        h[threadIdx.x] = 0;
        __syncthreads();
        int e0 = b * EPB;
        int e1 = e0 + EPB; if (e1 > N_EDGES) e1 = N_EDGES;
        for (int e = e0 + threadIdx.x; e < e1; e += 256)
            atomicAdd(&h[dst[e] >> 8], 1);
        __syncthreads();
        counts[b * 256 + threadIdx.x] = h[threadIdx.x];
    } else if (b < PB_HIST + PB_WPREP) {
        int idx = (b - PB_HIST) * 256 + threadIdx.x;
        int m = idx >> 14;
        int r = idx & 16383;
        int k = r >> 7;
        int n = r & 127;
        const float* W = (m == 0) ? lin_w : conv_W + (size_t)(m - 1) * 16384;
        float v = W[(size_t)k * 128 + n];
        int slot = (k >> 3) ^ (n & 15);
        wt_g[(size_t)m * 16384 + n * 128 + slot * 8 + (k & 7)] = (_Float16)v;
    } else if (b < PB_HIST + PB_WPREP + PB_APREP) {
        int idx = (b - PB_HIST - PB_WPREP) * 256 + threadIdx.x;
        int li = idx >> 11;
        int r = idx & 2047;
        int k = r >> 4;
        int n = r & 15;
        float v = 0.f;
        if (n < 8) {
            int hh = n & 3;
            const float* a = (n < 4) ? conv_asrc : conv_adst;
            const float* Wrow = conv_W + (size_t)li * 16384 + (size_t)k * 128 + hh * 32;
            const float* av = a + (size_t)li * 128 + hh * 32;
            #pragma unroll 8
            for (int d = 0; d < 32; ++d) v += Wrow[d] * av[d];
        }
        int slot = (k >> 3) ^ n;
        aux_g[(size_t)li * 2048 + n * 128 + slot * 8 + (k & 7)] = (_Float16)v;
    } else {
        int idx = (b - PB_HIST - PB_WPREP - PB_APREP) * 256 + threadIdx.x;
        pooled[idx] = 0.f;
    }
}

// ------------------------------------------------------------------
// MFMA GEMM + folded attention projections (1 aux MFMA tile).
// AF32: A is fp32 (input linear) -- converted in-register.
// ------------------------------------------------------------------
template <bool AF32>
__global__ __launch_bounds__(256) void k_gemm16(
    const void* __restrict__ Av, const _Float16* __restrict__ wt,
    const _Float16* __restrict__ aux, const float* __restrict__ bias,
    __half* __restrict__ C16, int M,
    float* __restrict__ a_s, float* __restrict__ a_d)
{
    __shared__ _Float16 Wt[128 * 128];
    __shared__ _Float16 Waux[16 * 128];
    int tid = threadIdx.x;
    {
        const float4* wsrc = (const float4*)wt;
        float4* wl = (float4*)Wt;
        #pragma unroll
        for (int r = 0; r < 8; ++r) wl[r * 256 + tid] = wsrc[r * 256 + tid];
        if (aux) ((float4*)Waux)[tid] = ((const float4*)aux)[tid];
    }
    __syncthreads();

    int lane = tid & 63;
    int wv = tid >> 6;
    int r0 = blockIdx.x * 64 + wv * 16;
    int cl = lane & 15;
    int ks = lane >> 4;

    int arow = r0 + cl; if (arow >= M) arow = M - 1;
    half8_t afrag[4];
    if (AF32) {
        const float* ArowF = (const float*)Av + (size_t)arow * 128 + ks * 8;
        #pragma unroll
        for (int kk = 0; kk < 4; ++kk) {
            float4 f0 = *(const float4*)(ArowF + kk * 32);
            float4 f1 = *(const float4*)(ArowF + kk * 32 + 4);
            half8_t a;
            a[0] = (_Float16)f0.x; a[1] = (_Float16)f0.y;
            a[2] = (_Float16)f0.z; a[3] = (_Float16)f0.w;
            a[4] = (_Float16)f1.x; a[5] = (_Float16)f1.y;
            a[6] = (_Float16)f1.z; a[7] = (_Float16)f1.w;
            afrag[kk] = a;
        }
    } else {
        const _Float16* Arow = (const _Float16*)Av + (size_t)arow * 128 + ks * 8;
        #pragma unroll
        for (int kk = 0; kk < 4; ++kk)
            afrag[kk] = *(const half8_t*)(Arow + kk * 32);
    }

    floatx4 acc[8];
    #pragma unroll
    for (int nt = 0; nt < 8; ++nt) acc[nt] = (floatx4){0.f, 0.f, 0.f, 0.f};

    #pragma unroll
    for (int kk = 0; kk < 4; ++kk) {
        #pragma unroll
        for (int nt = 0; nt < 8; ++nt) {
            int n = nt * 16 + cl;
            int slot = (kk * 4 + ks) ^ cl;
            half8_t bfrag = *(const half8_t*)&Wt[n * 128 + slot * 8];
            acc[nt] = __builtin_amdgcn_mfma_f32_16x16x32_f16(afrag[kk], bfrag, acc[nt], 0, 0, 0);
        }
    }

    int rg = lane >> 4;
    #pragma unroll
    for (int nt = 0; nt < 8; ++nt) {
        float bv = bias ? bias[nt * 16 + cl] : 0.f;
        #pragma unroll
        for (int j = 0; j < 4; ++j) {
            int row = r0 + rg * 4 + j;
            if (row < M)
                C16[(size_t)row * 128 + nt * 16 + cl] = __float2half(acc[nt][j] + bv);
        }
    }

    if (a_s) {
        floatx4 accP = (floatx4){0.f, 0.f, 0.f, 0.f};
        #pragma unroll
        for (int kk = 0; kk < 4; ++kk) {
            int slot = (kk * 4 + ks) ^ cl;
            half8_t bfrag = *(const half8_t*)&Waux[cl * 128 + slot * 8];
            accP = __builtin_amdgcn_mfma_f32_16x16x32_f16(afrag[kk], bfrag, accP, 0, 0, 0);
        }
        if (cl < 8) {
            float* dstp = (cl < 4) ? a_s : a_d;
            int h = cl & 3;
            #pragma unroll
            for (int j = 0; j < 4; ++j) {
                int row = r0 + rg * 4 + j;
                if (row < M) dstp[row * 4 + h] = accP[j];
            }
        }
    }
}

// ------------------------------------------------------------------
// CSR build (scan + bin + per-bucket counting sort).
// ------------------------------------------------------------------
__global__ __launch_bounds__(256) void k_scan2(const int* __restrict__ counts,
                                               int* __restrict__ base,
                                               int* __restrict__ bucketBase)
{
    __shared__ int tot[256];
    __shared__ int pref[257];
    int b = threadIdx.x;
    int s = 0;
    for (int blk = 0; blk < NBLK; ++blk) s += counts[blk * 256 + b];
    tot[b] = s;
    __syncthreads();
    if (b == 0) {
        int run = 0;
        for (int i = 0; i < 256; ++i) { pref[i] = run; run += tot[i]; }
        pref[256] = run;
    }
    __syncthreads();
    if (b <= NBUCK) bucketBase[b] = pref[b];
    int run = pref[b];
    for (int blk = 0; blk < NBLK; ++blk) {
        base[blk * 256 + b] = run;
        run += counts[blk * 256 + b];
    }
}

__global__ __launch_bounds__(256) void k_bin(const int* __restrict__ src,
                                             const int* __restrict__ dst,
                                             const float* __restrict__ ea,
                                             const int* __restrict__ base,
                                             int2* __restrict__ binned)
{
    __shared__ int cur[256];
    cur[threadIdx.x] = base[blockIdx.x * 256 + threadIdx.x];
    __syncthreads();
    int e0 = blockIdx.x * EPB;
    int e1 = e0 + EPB; if (e1 > N_EDGES) e1 = N_EDGES;
    for (int e = e0 + threadIdx.x; e < e1; e += 256) {
        int d = dst[e];
        int p = atomicAdd(&cur[d >> 8], 1);
        binned[p] = make_int2(src[e] | ((d & 255) << 16), __float_as_int(ea[e]));
    }
}

__global__ __launch_bounds__(256) void k_sortfill(const int2* __restrict__ binned,
                                                  const int* __restrict__ bucketBase,
                                                  int2* __restrict__ edata,
                                                  int* __restrict__ offs)
{
    __shared__ int bx[BCAP];
    __shared__ int by[BCAP];
    __shared__ int cnt[256];
    __shared__ int nb[256];
    int b = blockIdx.x;
    int p0 = bucketBase[b], p1 = bucketBase[b + 1];
    int m = p1 - p0;
    if (m > BCAP) m = BCAP;
    cnt[threadIdx.x] = 0;
    __syncthreads();
    for (int i = threadIdx.x; i < m; i += 256) {
        int2 v = binned[p0 + i];
        bx[i] = v.x; by[i] = v.y;
        atomicAdd(&cnt[(v.x >> 16) & 255], 1);
    }
    __syncthreads();
    if (threadIdx.x == 0) {
        int run = 0;
        for (int i = 0; i < 256; ++i) { nb[i] = run; run += cnt[i]; }
    }
    __syncthreads();
    int node = b * 256 + threadIdx.x;
    if (node < N_NODES) offs[node] = p0 + nb[threadIdx.x];
    if (b == NBUCK - 1 && threadIdx.x == 0) offs[N_NODES] = p1;
    __syncthreads();
    cnt[threadIdx.x] = nb[threadIdx.x];
    __syncthreads();
    for (int i = threadIdx.x; i < m; i += 256) {
        int dl = (bx[i] >> 16) & 255;
        int pos = atomicAdd(&cnt[dl], 1);
        edata[p0 + pos] = make_int2(bx[i] & 0xFFFF, by[i]);
    }
}

// ------------------------------------------------------------------
// Fused attention aggregation, 2 nodes per wave (R12 layout).
// ------------------------------------------------------------------
__global__ __launch_bounds__(256) void k_attn4(
    const __half* __restrict__ wx16, const int2* __restrict__ edata,
    const float* __restrict__ a_s, const float* __restrict__ a_d,
    const int* __restrict__ offs, const __half* __restrict__ resid,
    __half* __restrict__ out)
{
    int lane = threadIdx.x & 63;
    int wid = threadIdx.x >> 6;
    int nh = lane >> 5;
    int n = blockIdx.x * 8 + wid * 2 + nh;
    int q = (lane >> 3) & 3;
    int cl = lane & 7;
    int c0 = cl * 16;
    int ht = cl >> 1;
    int off0 = offs[n], off1 = offs[n + 1];
    int cnt = off1 - off0;
    float adn = a_d[n * 4 + ht];
    const _Float16* wx = (const _Float16*)wx16;

    float den = 0.f;
    float acc[16];
    #pragma unroll
    for (int k = 0; k < 16; ++k) acc[k] = 0.f;

    #define STEP(jj) {                                                         \
        int2 ed = edata[off0 + (jj)];                                          \
        float t = a_s[ed.x * 4 + ht] + adn;                                    \
        t = (t > 0.f ? t : 0.2f * t) * __int_as_float(ed.y);                   \
        float w = __expf(fminf(t, 80.f));                                      \
        den += w;                                                              \
        const _Float16* rp = &wx[(size_t)ed.x * 128 + c0];                     \
        half8_t g0 = *(const half8_t*)rp;                                      \
        half8_t g1 = *(const half8_t*)(rp + 8);                                \
        acc[0]  += w * (float)g0[0]; acc[1]  += w * (float)g0[1];              \
        acc[2]  += w * (float)g0[2]; acc[3]  += w * (float)g0[3];              \
        acc[4]  += w * (float)g0[4]; acc[5]  += w * (float)g0[5];              \
        acc[6]  += w * (float)g0[6]; acc[7]  += w * (float)g0[7];              \
        acc[8]  += w * (float)g1[0]; acc[9]  += w * (float)g1[1];              \
        acc[10] += w * (float)g1[2]; acc[11] += w * (float)g1[3];              \
        acc[12] += w * (float)g1[4]; acc[13] += w * (float)g1[5];              \
        acc[14] += w * (float)g1[6]; acc[15] += w * (float)g1[7]; }

    int j = q;
    for (; j + 4 < cnt; j += 8) { STEP(j); STEP(j + 4); }
    if (j < cnt) STEP(j);
    #undef STEP

    den += __shfl_xor(den, 8);
    den += __shfl_xor(den, 16);
    #pragma unroll
    for (int k = 0; k < 16; ++k) {
        acc[k] += __shfl_xor(acc[k], 8);
        acc[k] += __shfl_xor(acc[k], 16);
    }

    if (q == 0) {
        float inv = 1.f / (den + 1e-16f);
        const _Float16* rvp = resid ? (const _Float16*)resid + (size_t)n * 128 + c0 : nullptr;
        half8_t rv0, rv1;
        if (resid) { rv0 = *(const half8_t*)rvp; rv1 = *(const half8_t*)(rvp + 8); }
        half8_t o0, o1;
        #pragma unroll
        for (int k = 0; k < 8; ++k) {
            float r = acc[k] * inv;
            r = r > 0.f ? r : (__expf(r) - 1.f);
            if (resid) r += (float)rv0[k];
            o0[k] = (_Float16)r;
        }
        #pragma unroll
        for (int k = 0; k < 8; ++k) {
            float r = acc[8 + k] * inv;
            r = r > 0.f ? r : (__expf(r) - 1.f);
            if (resid) r += (float)rv1[k];
            o1[k] = (_Float16)r;
        }
        _Float16* op = (_Float16*)out + (size_t)n * 128 + c0;
        *(half8_t*)op = o0;
        *(half8_t*)(op + 8) = o1;
    }
}

// ------------------------------------------------------------------
// Pool: chunked partial sums + atomic flush at segment boundaries.
// ------------------------------------------------------------------
__global__ __launch_bounds__(256) void k_pool2(
    const __half* __restrict__ h, const int* __restrict__ batch,
    float* __restrict__ pooled)
{
    int c = threadIdx.x & 127;
    int hf = threadIdx.x >> 7;
    int n0 = blockIdx.x * 64 + hf * 32;
    if (n0 >= N_NODES) return;
    int nend = n0 + 32; if (nend > N_NODES) nend = N_NODES;

    int g = batch[n0];
    float acc = 0.f;
    for (int n = n0; n < nend; ++n) {
        int bg = batch[n];
        if (bg != g) { atomicAdd(&pooled[g * 128 + c], acc); acc = 0.f; g = bg; }
        acc += __half2float(h[(size_t)n * 128 + c]);
    }
    atomicAdd(&pooled[g * 128 + c], acc);
}

// ------------------------------------------------------------------
// Linear + BatchNorm (+relu)
// ------------------------------------------------------------------
template <int K, int OC>
__global__ __launch_bounds__(256) void k_mlp(
    const float* __restrict__ in, const float* __restrict__ w,
    const float* __restrict__ b, const float* __restrict__ gam,
    const float* __restrict__ bet, float* __restrict__ out, int do_relu)
{
    __shared__ float2 red[256];
    int c = blockIdx.x, g = threadIdx.x;
    float val = b[c];
    #pragma unroll 8
    for (int k = 0; k < K; ++k) val += in[g * K + k] * w[k * OC + c];
    red[g] = make_float2(val, val * val);
    __syncthreads();
    for (int s = 128; s > 0; s >>= 1) {
        if (g < s) { red[g].x += red[g + s].x; red[g].y += red[g + s].y; }
        __syncthreads();
    }
    float mean = red[0].x * (1.f / 256.f);
    float var = red[0].y * (1.f / 256.f) - mean * mean;
    float y = (val - mean) * rsqrtf(var + 1e-5f) * gam[c] + bet[c];
    if (do_relu) y = fmaxf(y, 0.f);
    out[g * OC + c] = y;
}

// ------------------------------------------------------------------
extern "C" void kernel_launch(void* const* d_in, const int* in_sizes, int n_in,
                              void* d_out, int out_size, void* d_ws, size_t ws_size,
                              hipStream_t stream)
{
    const float* x         = (const float*)d_in[0];
    const float* edge_attr = (const float*)d_in[1];
    const float* lin_w     = (const float*)d_in[2];
    const float* lin_b     = (const float*)d_in[3];
    const float* conv_W    = (const float*)d_in[4];
    const float* conv_asrc = (const float*)d_in[5];
    const float* conv_adst = (const float*)d_in[6];
    const float* fc_w1 = (const float*)d_in[7];
    const float* fc_b1 = (const float*)d_in[8];
    const float* bn_g1 = (const float*)d_in[9];
    const float* bn_b1 = (const float*)d_in[10];
    const float* fc_w2 = (const float*)d_in[11];
    const float* fc_b2 = (const float*)d_in[12];
    const float* bn_g2 = (const float*)d_in[13];
    const float* bn_b2 = (const float*)d_in[14];
    const float* fc_w3 = (const float*)d_in[15];
    const float* fc_b3 = (const float*)d_in[16];
    const float* bn_g3 = (const float*)d_in[17];
    const float* bn_b3 = (const float*)d_in[18];
    const int* edge_index = (const int*)d_in[19];
    const int* batch      = (const int*)d_in[20];
    const int* srcp = edge_index;
    const int* dstp = edge_index + N_EDGES;
    float* out = (float*)d_out;

    char* ws = (char*)d_ws;
    __half* h_cur = (__half*)ws; ws += (size_t)N_NODES * 128 * 2;
    __half* h_tmp = (__half*)ws; ws += (size_t)N_NODES * 128 * 2;
    __half* wx16  = (__half*)ws; ws += (size_t)N_NODES * 128 * 2;
    float* a_s   = (float*)ws;  ws += (size_t)N_NODES * 4 * 4;
    float* a_d   = (float*)ws;  ws += (size_t)N_NODES * 4 * 4;
    float* pooled= (float*)ws;  ws += (size_t)NGRAPH * 128 * 4;
    float* z1    = (float*)ws;  ws += (size_t)NGRAPH * 64 * 4;
    float* z2    = (float*)ws;  ws += (size_t)NGRAPH * 32 * 4;
    int* offs    = (int*)ws;    ws += (size_t)(N_NODES + 4) * 4;
    int2* edata  = (int2*)ws;   ws += (size_t)N_EDGES * 8;
    int2* binned = (int2*)ws;   ws += (size_t)N_EDGES * 8;
    int* counts  = (int*)ws;    ws += (size_t)NBLK * 256 * 4;
    int* base    = (int*)ws;    ws += (size_t)NBLK * 256 * 4;
    int* bucketBase = (int*)ws; ws += 256 * 4;
    _Float16* wt_g = (_Float16*)ws; ws += (size_t)7 * 16384 * 2;
    _Float16* wt_aux = (_Float16*)ws; ws += (size_t)6 * 2048 * 2;

    // --- fused prologue + CSR build ---
    k_prep<<<PREP_GRID, 256, 0, stream>>>(dstp, counts, lin_w, conv_W, wt_g,
                                          conv_asrc, conv_adst, wt_aux, pooled);
    k_scan2<<<1, 256, 0, stream>>>(counts, base, bucketBase);
    k_bin<<<NBLK, 256, 0, stream>>>(srcp, dstp, edge_attr, base, binned);
    k_sortfill<<<NBUCK, 256, 0, stream>>>(binned, bucketBase, edata, offs);

    const int GGRID = (N_NODES + 63) / 64;
    const int AGRID = (N_NODES + 7) / 8;

    // --- input linear (reads fp32 x directly) ---
    k_gemm16<true><<<GGRID, 256, 0, stream>>>(x, wt_g, nullptr, lin_b, h_cur,
                                              N_NODES, nullptr, nullptr);

    // --- 3 residual scatter convs, 2 inner layers each ---
    for (int i = 0; i < 3; ++i) {
        const _Float16* W0 = wt_g + (size_t)(1 + i * 2 + 0) * 16384;
        const _Float16* W1 = wt_g + (size_t)(1 + i * 2 + 1) * 16384;
        const _Float16* X0 = wt_aux + (size_t)(i * 2 + 0) * 2048;
        const _Float16* X1 = wt_aux + (size_t)(i * 2 + 1) * 2048;

        k_gemm16<false><<<GGRID, 256, 0, stream>>>(h_cur, W0, X0, nullptr, wx16,
                                                   N_NODES, a_s, a_d);
        k_attn4<<<AGRID, 256, 0, stream>>>(wx16, edata, a_s, a_d,
                                           offs, nullptr, h_tmp);

        k_gemm16<false><<<GGRID, 256, 0, stream>>>(h_tmp, W1, X1, nullptr, wx16,
                                                   N_NODES, a_s, a_d);
        k_attn4<<<AGRID, 256, 0, stream>>>(wx16, edata, a_s, a_d,
                                           offs, h_cur, h_cur);
    }

    // --- pool + MLP head ---
    k_pool2<<<GGRID, 256, 0, stream>>>(h_cur, batch, pooled);
    k_mlp<128, 64><<<64, 256, 0, stream>>>(pooled, fc_w1, fc_b1, bn_g1, bn_b1, z1, 1);
    k_mlp<64, 32><<<32, 256, 0, stream>>>(z1, fc_w2, fc_b2, bn_g2, bn_b2, z2, 1);
    k_mlp<32, 10><<<10, 256, 0, stream>>>(z2, fc_w3, fc_b3, bn_g3, bn_b3, out, 0);
}